// Round 18
// baseline (339.680 us; speedup 1.0000x reference)
//
#include <hip/hip_runtime.h>
#include <stdint.h>

#define DEVI __device__ __forceinline__

typedef __attribute__((ext_vector_type(8))) uint16_t u16x8;
typedef __attribute__((ext_vector_type(4))) uint16_t u16x4v;
typedef __attribute__((ext_vector_type(4))) uint32_t u32x4;
typedef __attribute__((ext_vector_type(8))) __bf16 bf16x8;
typedef __attribute__((ext_vector_type(4))) float f32x4;
typedef __attribute__((ext_vector_type(16))) float f32x16;

DEVI uint16_t f2bf(float x) {
  union { float f; uint32_t u; } v; v.f = x;
  return (uint16_t)((v.u + 0x7fffu + ((v.u >> 16) & 1u)) >> 16);
}

DEVI uint16_t f2bfn(float f) {
  __bf16 h = (__bf16)f;
  return __builtin_bit_cast(uint16_t, h);
}

DEVI f32x4 mfma16(u16x8 a, u16x8 b, f32x4 c) {
  return __builtin_amdgcn_mfma_f32_16x16x32_bf16(
      __builtin_bit_cast(bf16x8, a), __builtin_bit_cast(bf16x8, b), c, 0, 0, 0);
}

DEVI f32x16 mfma32(u16x8 a, u16x8 b, f32x16 c) {
  return __builtin_amdgcn_mfma_f32_32x32x16_bf16(
      __builtin_bit_cast(bf16x8, a), __builtin_bit_cast(bf16x8, b), c, 0, 0, 0);
}

DEVI void async16(void* lds, const void* g) {
  __builtin_amdgcn_global_load_lds(
      (const __attribute__((address_space(1))) uint32_t*)g,
      (__attribute__((address_space(3))) uint32_t*)lds, 16, 0, 0);
}

// 1/sqrt(128) * log2(e): softmax computed in exp2 domain, scale folded into Q.
#define QSC 0.12751742925f

// ---------------- elementwise f32 -> bf16 ----------------
__global__ void cvt_f32_bf16(const float* __restrict__ in, uint16_t* __restrict__ out, int n4) {
  int i = blockIdx.x * blockDim.x + threadIdx.x;
  const int st = gridDim.x * blockDim.x;
  for (; i < n4; i += st) {
    float4 v = ((const float4*)in)[i];
    u16x4v o;
    o[0] = f2bf(v.x); o[1] = f2bf(v.y); o[2] = f2bf(v.z); o[3] = f2bf(v.w);
    ((u16x4v*)out)[i] = o;
  }
}

// ------------- transpose + convert: f32 [K][N] -> bf16 [N][K] -------------
__global__ void transp_cvt(const float* __restrict__ in, uint16_t* __restrict__ out,
                           int K, int N) {
  __shared__ float Ws[64][65];
  const int n0 = blockIdx.x * 64, k0 = blockIdx.y * 64;
  const int t = threadIdx.x;
  const int r = t >> 4, c = (t & 15) << 2;
#pragma unroll
  for (int it = 0; it < 4; ++it) {
    float4 v = *(const float4*)&in[(size_t)(k0 + it * 16 + r) * N + n0 + c];
    Ws[it * 16 + r][c] = v.x; Ws[it * 16 + r][c + 1] = v.y;
    Ws[it * 16 + r][c + 2] = v.z; Ws[it * 16 + r][c + 3] = v.w;
  }
  __syncthreads();
#pragma unroll
  for (int it = 0; it < 4; ++it) {
    const int rr = it * 16 + r;   // n index in tile
    const int cc = c;             // k index in tile
    ushort4 o;
    o.x = f2bf(Ws[cc][rr]);     o.y = f2bf(Ws[cc + 1][rr]);
    o.z = f2bf(Ws[cc + 2][rr]); o.w = f2bf(Ws[cc + 3][rr]);
    *(ushort4*)&out[(size_t)(n0 + rr) * K + k0 + cc] = o;
  }
}

// ------ qkv GEMM: 256x128 tile, DEEP-COVER pipeline (round-18) ------
// A TRIPLE-buffered (3x32K), B double (2x16K), LDS 128 KB. Per K-tile t:
//  p0: read all B(t) frags + A(t) p0-half; barrier; 16 MFMA; barrier.
//  p1: read A(t) p1-half; issue A(t+2)->abuf[(cA+2)%3], B(t+2)->bbuf[t&1]
//      (B(t)'s space is dead: all B(t) ds_reads completed before p0's end
//      barrier, and the glds issues after it); vmcnt(6) = newest 6 in flight
//      (A(t+2)4+B(t+2)2) -> proves A(t+1),B(t+1) landed with TWO full phases
//      of cover (~1600+ cyc vs round-17's half-phase ~600 -> the 1690-cyc
//      phase cost vs proj's 1030); barrier; 16 MFMA; barrier.
// Invariant chain: at p1 of tile t, outstanding = {A(t+1),B(t+1)} (left by
// vmcnt(6) at p1 of t-1); issue 6 more; vmcnt(6) drains the older 6. Tail:
// vmcnt(0) when t+2 >= nt. Prologue stages tiles 0,1 + vmcnt(0).
// V^T fused epilogue (round-16, verified). T2 chunk swizzle both-sides.
__global__ __launch_bounds__(512, 1)
void gemm_qkv(const uint16_t* __restrict__ A, const uint16_t* __restrict__ Bt,
              const float* __restrict__ bias,
              uint16_t* __restrict__ q, uint16_t* __restrict__ kk, uint16_t* __restrict__ vt,
              int M, int N, int K) {
  constexpr int BK = 64;
  __shared__ uint16_t As[3][256 * BK];   // 96 KB (triple)
  __shared__ uint16_t Bs[2][128 * BK];   // 32 KB (double)
  int bid = (int)blockIdx.x;
  const int q8 = (int)gridDim.x >> 3;
  bid = (bid & 7) * q8 + (bid >> 3);
  const int nbn = N >> 7;
  const int brow = (bid / nbn) << 8;
  const int bcol = (bid % nbn) << 7;
  const int t = threadIdx.x;
  const int wid = t >> 6, lane = t & 63;
  const int wm = wid >> 1, wn = wid & 1;          // 4 x 2 wave grid
  const int lr = lane & 15, g = lane >> 4, l7 = lr & 7;

  const int logch = (((t & 7) ^ ((t >> 3) & 7)) << 3);
  const uint16_t* Asrc = A + (size_t)(brow + (t >> 3)) * K + logch;
  const uint16_t* Bsrc = Bt + (size_t)(bcol + (t >> 3)) * K + logch;
  const size_t skip64 = (size_t)64 * K;
  const int dt = t * 8;

  auto stageA = [&](int buf, int k0) {
#pragma unroll
    for (int l = 0; l < 4; ++l)
      async16(&As[buf][l * 4096 + dt], Asrc + (size_t)l * skip64 + k0);
  };
  auto stageB = [&](int buf, int k0) {
#pragma unroll
    for (int l = 0; l < 2; ++l)
      async16(&Bs[buf][l * 4096 + dt], Bsrc + (size_t)l * skip64 + k0);
  };

  f32x4 acc[4][4];
#pragma unroll
  for (int i = 0; i < 4; ++i)
#pragma unroll
    for (int j = 0; j < 4; ++j) acc[i][j] = f32x4{0.f, 0.f, 0.f, 0.f};

  const int nt = K / BK;
  // prologue: tiles 0 and 1 fully staged, single drain.
  stageA(0, 0); stageB(0, 0);
  if (nt > 1) { stageA(1, BK); stageB(1, BK); }
  asm volatile("s_waitcnt vmcnt(0)" ::: "memory");
  __builtin_amdgcn_s_barrier();

  int cA = 0;                                     // A buffer of current tile
  for (int tt = 0; tt < nt; ++tt) {
    const int bbuf = tt & 1;
    u16x8 bfr[4][2];
    // ---- phase 0: all B frags + A rows 0..31 ----
#pragma unroll
    for (int j = 0; j < 4; ++j) {
      const int brw = wn * 64 + j * 16 + lr;
#pragma unroll
      for (int s = 0; s < 2; ++s)
        bfr[j][s] = *(const u16x8*)&Bs[bbuf][brw * 64 + ((((s << 2) + g) ^ l7) << 3)];
    }
    u16x8 af[2][2];
#pragma unroll
    for (int ii = 0; ii < 2; ++ii) {
      const int arow = wm * 64 + ii * 16 + lr;
#pragma unroll
      for (int s = 0; s < 2; ++s)
        af[ii][s] = *(const u16x8*)&As[cA][arow * 64 + ((((s << 2) + g) ^ l7) << 3)];
    }
    __builtin_amdgcn_s_barrier();
    __builtin_amdgcn_s_setprio(1);
#pragma unroll
    for (int ii = 0; ii < 2; ++ii)
#pragma unroll
      for (int j = 0; j < 4; ++j)
#pragma unroll
        for (int s = 0; s < 2; ++s)
          acc[ii][j] = mfma16(af[ii][s], bfr[j][s], acc[ii][j]);
    __builtin_amdgcn_s_setprio(0);
    __builtin_amdgcn_s_barrier();
    // ---- phase 1: A rows 32..63; stage tile t+2; counted wait ----
#pragma unroll
    for (int ii = 0; ii < 2; ++ii) {
      const int arow = wm * 64 + (2 + ii) * 16 + lr;
#pragma unroll
      for (int s = 0; s < 2; ++s)
        af[ii][s] = *(const u16x8*)&As[cA][arow * 64 + ((((s << 2) + g) ^ l7) << 3)];
    }
    if (tt + 2 < nt) {
      int cA2 = cA + 2; if (cA2 >= 3) cA2 -= 3;
      stageA(cA2, (tt + 2) * BK);
      stageB(bbuf, (tt + 2) * BK);
      asm volatile("s_waitcnt vmcnt(6)" ::: "memory");
    } else {
      asm volatile("s_waitcnt vmcnt(0)" ::: "memory");
    }
    __builtin_amdgcn_s_barrier();
    __builtin_amdgcn_s_setprio(1);
#pragma unroll
    for (int ii = 0; ii < 2; ++ii)
#pragma unroll
      for (int j = 0; j < 4; ++j)
#pragma unroll
        for (int s = 0; s < 2; ++s)
          acc[2 + ii][j] = mfma16(af[ii][s], bfr[j][s], acc[2 + ii][j]);
    __builtin_amdgcn_s_setprio(0);
    __builtin_amdgcn_s_barrier();
    cA = (cA + 1 == 3) ? 0 : cA + 1;
  }

#pragma unroll
  for (int i = 0; i < 4; ++i) {
#pragma unroll
    for (int j = 0; j < 4; ++j) {
      const int col = bcol + wn * 64 + j * 16 + lr;
      const float bb = bias[col];
      const int rowb = brow + wm * 64 + i * 16 + (g << 2);
      const int b_ = rowb >> 11, ttb = rowb & 2047;   // r-span stays in one seq
      const int d = col & 127;
      float vals[4];
#pragma unroll
      for (int r = 0; r < 4; ++r) vals[r] = acc[i][j][r] + bb;
      if (col < 2048) {
        const int hh = col >> 7;
#pragma unroll
        for (int r = 0; r < 4; ++r)
          q[((size_t)((b_ * 16 + hh) * 2048 + ttb + r) << 7) + d] = f2bf(vals[r] * QSC);
      } else if (col < 2560) {
        const int hh = (col - 2048) >> 7;
#pragma unroll
        for (int r = 0; r < 4; ++r)
          kk[((size_t)((b_ * 4 + hh) * 2048 + ttb + r) << 7) + d] = f2bf(vals[r]);
      } else {
        const int hh = (col - 2560) >> 7;
        u16x4v pk;
#pragma unroll
        for (int r = 0; r < 4; ++r) pk[r] = f2bf(vals[r]);
        *(u16x4v*)&vt[(((size_t)((b_ * 4 + hh) * 128 + d)) << 11) + ttb] = pk;
      }
    }
  }
}

// ------------- proj GEMM: 8-phase 256x256 schedule (round-11, verified) -----
__global__ __launch_bounds__(512, 1)
void gemm_proj(const uint16_t* __restrict__ A, const uint16_t* __restrict__ Bt,
               const float* __restrict__ bias, float* __restrict__ outF,
               int M, int N, int K) {
  constexpr int BK = 64;
  __shared__ uint16_t As[2][256 * BK];   // 64 KB
  __shared__ uint16_t Bs[2][256 * BK];   // 64 KB
  int bid = (int)blockIdx.x;
  const int q8 = (int)gridDim.x >> 3;
  bid = (bid & 7) * q8 + (bid >> 3);
  const int nbn = N >> 8;
  const int brow = (bid / nbn) << 8;
  const int bcol = (bid % nbn) << 8;
  const int t = threadIdx.x;
  const int wid = t >> 6, lane = t & 63;
  const int wm = wid >> 2, wn = wid & 3;          // 2 x 4 wave grid
  const int lr = lane & 15, g = lane >> 4;
  const int l7 = lr & 7;

  const int sr0 = t >> 3;
  const int logch = (((t & 7) ^ ((t >> 3) & 7)) << 3);
  const uint16_t* Asrc0 = A + (size_t)(brow + sr0) * K + logch;
  const uint16_t* Asrc1 = A + (size_t)(brow + 64 + sr0) * K + logch;
  const uint16_t* Bsrc0 = Bt + (size_t)(bcol + sr0) * K + logch;
  const uint16_t* Bsrc1 = Bt + (size_t)(bcol + 64 + sr0) * K + logch;
  const size_t hskip = (size_t)128 * K;
  const int d0 = t * 8, d1 = 4096 + t * 8;

  auto stageA = [&](int buf, int h, int k0) {
    async16(&As[buf][h * 8192 + d0], Asrc0 + (size_t)h * hskip + k0);
    async16(&As[buf][h * 8192 + d1], Asrc1 + (size_t)h * hskip + k0);
  };
  auto stageB = [&](int buf, int h, int k0) {
    async16(&Bs[buf][h * 8192 + d0], Bsrc0 + (size_t)h * hskip + k0);
    async16(&Bs[buf][h * 8192 + d1], Bsrc1 + (size_t)h * hskip + k0);
  };

  f32x4 acc[8][4];
#pragma unroll
  for (int i = 0; i < 8; ++i)
#pragma unroll
    for (int j = 0; j < 4; ++j) acc[i][j] = f32x4{0.f, 0.f, 0.f, 0.f};

  const int nt = K / BK;
  stageA(0, 0, 0); stageA(0, 1, 0);
  stageB(0, 0, 0); stageB(0, 1, 0);
  if (nt > 1) { stageB(1, 0, BK); stageB(1, 1, BK); }
  asm volatile("s_waitcnt vmcnt(0)" ::: "memory");
  __builtin_amdgcn_s_barrier();

  for (int tt = 0; tt < nt; ++tt) {
    const int buf = tt & 1;
    u16x8 bfr[4][2];
#pragma unroll
    for (int p = 0; p < 4; ++p) {
      if (p == 0) {
#pragma unroll
        for (int j = 0; j < 4; ++j) {
          const int brw = wn * 64 + j * 16 + lr;
#pragma unroll
          for (int s = 0; s < 2; ++s)
            bfr[j][s] = *(const u16x8*)&Bs[buf][brw * 64 + ((((s << 2) + g) ^ l7) << 3)];
        }
      }
      u16x8 af[2][2];
#pragma unroll
      for (int ii = 0; ii < 2; ++ii) {
        const int arow = wm * 128 + (p * 2 + ii) * 16 + lr;
#pragma unroll
        for (int s = 0; s < 2; ++s)
          af[ii][s] = *(const u16x8*)&As[buf][arow * 64 + ((((s << 2) + g) ^ l7) << 3)];
      }
      if (p == 0) { if (tt + 1 < nt) stageA(buf ^ 1, 0, (tt + 1) * BK); }
      if (p == 1) { if (tt + 1 < nt) stageA(buf ^ 1, 1, (tt + 1) * BK); }
      if (p == 2) { if (tt + 2 < nt) stageB(buf, 0, (tt + 2) * BK); }
      if (p == 3) {
        if (tt + 2 < nt) {
          stageB(buf, 1, (tt + 2) * BK);
          asm volatile("s_waitcnt vmcnt(4)" ::: "memory");
        } else {
          asm volatile("s_waitcnt vmcnt(0)" ::: "memory");
        }
      }
      __builtin_amdgcn_s_barrier();
      __builtin_amdgcn_s_setprio(1);
#pragma unroll
      for (int ii = 0; ii < 2; ++ii)
#pragma unroll
        for (int j = 0; j < 4; ++j)
#pragma unroll
          for (int s = 0; s < 2; ++s)
            acc[p * 2 + ii][j] = mfma16(af[ii][s], bfr[j][s], acc[p * 2 + ii][j]);
      __builtin_amdgcn_s_setprio(0);
      __builtin_amdgcn_s_barrier();
    }
  }

#pragma unroll
  for (int i = 0; i < 8; ++i) {
#pragma unroll
    for (int j = 0; j < 4; ++j) {
      const int col = bcol + wn * 64 + j * 16 + lr;
      const float bb = bias[col];
#pragma unroll
      for (int r = 0; r < 4; ++r) {
        const int row = brow + wm * 128 + i * 16 + (g << 2) + r;
        outF[(size_t)row * N + col] = acc[i][j][r] + bb;
      }
    }
  }
}

// ------------- flash attention (causal, GQA 4:1) -------------
// ROUND-15 attn verbatim (best verified: 137 us, 92 VGPR, no spill).
__global__ __launch_bounds__(512, 1)
void attn_fwd(const uint16_t* __restrict__ Q,   // [B*16][T][128], pre-scaled by QSC
              const uint16_t* __restrict__ Kg,  // [B*4][T][128]
              const uint16_t* __restrict__ Vt,  // [B*4][128][T]
              uint16_t* __restrict__ Y,         // [B*T][2048], col offset h*128
              int T) {
  __shared__ __align__(16) uint16_t Ks[2][64 * 128];   // 32 KB (dbuf)
  __shared__ __align__(16) uint16_t Vs[128 * 64];      // 16 KB (single)
  const int id = (int)blockIdx.x;
  const int x = id & 7;
  const int h = (id >> 3) & 15, b = (id >> 7) & 3;
  const int qb = (id & 256) ? 7 - x : x;      // complementary across bit 8
  const int hkv = h >> 2;

  const int t = threadIdx.x, w = t >> 6, lane = t & 63;
  const int ql = lane & 31, b5 = lane >> 5;
  const int swzK = (ql & 15) << 3;
  const int swzV = (ql & 7) << 3;

  const uint16_t* Qp = Q + ((size_t)(b * 16 + h) * T + qb * 256) * 128;
  const uint16_t* Kp = Kg + (size_t)(b * 4 + hkv) * T * 128;
  const uint16_t* Vp = Vt + (size_t)(b * 4 + hkv) * 128 * T;

  auto stageK = [&](int buf, int kv0) {
#pragma unroll
    for (int l = 0; l < 2; ++l) {
      const int s = l * 512 + t;
      const int row = s >> 4;                       // 0..63
      const int cl = (s & 15) ^ (row & 15);
      async16(&Ks[buf][s * 8], &Kp[(size_t)(kv0 + row) * 128 + cl * 8]);
    }
  };
  auto stageV = [&](int kv0) {
#pragma unroll
    for (int l = 0; l < 2; ++l) {
      const int s = l * 512 + t;
      const int row = s >> 3;                       // 0..127
      const int cl = (s & 7) ^ (row & 7);
      async16(&Vs[s * 8], &Vp[(size_t)row * T + kv0 + cl * 8]);
    }
  };

  const int row0 = qb * 256 + w * 32;
  const int qrow = row0 + ql;

  u16x8 qf[8];
#pragma unroll
  for (int kc = 0; kc < 8; ++kc)
    qf[kc] = *(const u16x8*)&Qp[(size_t)(w * 32 + ql) * 128 + kc * 16 + b5 * 8];

  f32x16 o[4];  // O^T: lane holds O[d=32db+(reg&3)+8(reg>>2)+4b5][q=ql]
#pragma unroll
  for (int db = 0; db < 4; ++db)
#pragma unroll
    for (int r = 0; r < 16; ++r) o[db][r] = 0.f;
  float mrow = -3e38f, lrow = 0.f;

  const int ntiles = 4 * qb + 4;
  const int myn = 4 * qb + (w >> 1) + 1;  // waves skip fully-masked tail tiles

  stageK(0, 0);
  __syncthreads();

  int cur = 0;
  for (int tile = 0; tile < ntiles; ++tile) {
    const int kv0 = tile << 6;
    stageV(kv0);
    if (tile + 1 < ntiles) stageK(cur ^ 1, (tile + 1) << 6);

    const bool run = tile < myn;
    f32x16 s[2];
    u16x8 pa[4];
    if (run) {
#pragma unroll
      for (int m = 0; m < 2; ++m)
#pragma unroll
        for (int r = 0; r < 16; ++r) s[m][r] = 0.f;
      __builtin_amdgcn_s_setprio(1);
#pragma unroll
      for (int kc = 0; kc < 8; ++kc) {
        const int cc = (kc * 16 + b5 * 8) ^ swzK;
        u16x8 k0f = *(const u16x8*)&Ks[cur][ql * 128 + cc];
        u16x8 k1f = *(const u16x8*)&Ks[cur][(32 + ql) * 128 + cc];
        s[0] = mfma32(k0f, qf[kc], s[0]);
        s[1] = mfma32(k1f, qf[kc], s[1]);
      }
      __builtin_amdgcn_s_setprio(0);

      // causal mask
      if (kv0 + 63 > row0) {
#pragma unroll
        for (int m = 0; m < 2; ++m)
#pragma unroll
          for (int r = 0; r < 16; ++r) {
            const int kg = kv0 + 32 * m + (r & 3) + 8 * (r >> 2) + 4 * b5;
            if (kg > qrow) s[m][r] = -3e38f;
          }
      }
      // online softmax: tree max (dep depth 5)
      float mt[16];
#pragma unroll
      for (int r = 0; r < 16; ++r) mt[r] = fmaxf(s[0][r], s[1][r]);
#pragma unroll
      for (int st = 8; st >= 1; st >>= 1)
#pragma unroll
        for (int r = 0; r < st; ++r) mt[r] = fmaxf(mt[r], mt[r + st]);
      float mx = fmaxf(mt[0], __shfl_xor(mt[0], 32));
      // defer-max (THR=8)
      const bool defer = __all(mx <= mrow + 8.f);
      const float mnew = defer ? mrow : fmaxf(mrow, mx);
      const float sc = defer ? 1.f : exp2f(mrow - mnew);
#pragma unroll
      for (int m = 0; m < 2; ++m)
#pragma unroll
        for (int r = 0; r < 16; ++r) s[m][r] = exp2f(s[m][r] - mnew);
      // tree sum (dep depth 5)
      float pt[16];
#pragma unroll
      for (int r = 0; r < 16; ++r) pt[r] = s[0][r] + s[1][r];
#pragma unroll
      for (int st = 8; st >= 1; st >>= 1)
#pragma unroll
        for (int r = 0; r < st; ++r) pt[r] += pt[r + st];
      float ps = pt[0] + __shfl_xor(pt[0], 32);
      mrow = mnew;
      lrow = lrow * sc + ps;
      if (!defer) {
#pragma unroll
        for (int db = 0; db < 4; ++db)
#pragma unroll
          for (int r = 0; r < 16; ++r) o[db][r] *= sc;
      }

      // P -> B-operand fragments, fully in-register (cross-b5 exchange only)
#pragma unroll
      for (int m = 0; m < 2; ++m) {
        uint32_t pw[4][2];
#pragma unroll
        for (int a = 0; a < 4; ++a)
#pragma unroll
          for (int hh = 0; hh < 2; ++hh)
            pw[a][hh] = (uint32_t)f2bfn(s[m][4 * a + 2 * hh]) |
                        ((uint32_t)f2bfn(s[m][4 * a + 2 * hh + 1]) << 16);
#pragma unroll
        for (int c = 0; c < 2; ++c) {
          uint32_t wd[4];
#pragma unroll
          for (int hh = 0; hh < 2; ++hh) {
            const uint32_t mine  = b5 ? pw[2 * c + 1][hh] : pw[2 * c][hh];
            const uint32_t yours = b5 ? pw[2 * c][hh] : pw[2 * c + 1][hh];
            const uint32_t xw = (uint32_t)__shfl_xor((int)yours, 32);
            wd[hh] = b5 ? xw : mine;
            wd[2 + hh] = b5 ? mine : xw;
          }
          u32x4 tmp = {wd[0], wd[1], wd[2], wd[3]};
          pa[2 * m + c] = __builtin_bit_cast(u16x8, tmp);
        }
      }
    }
    __syncthreads();   // drains V(t) (+K(t+1)); all QK reads of Ks[cur] done

    if (run) {
      __builtin_amdgcn_s_setprio(1);
#pragma unroll
      for (int db = 0; db < 4; ++db) {
#pragma unroll
        for (int kf = 0; kf < 4; ++kf) {
          u16x8 vf = *(const u16x8*)&Vs[(32 * db + ql) * 64 +
                                        ((kf * 16 + b5 * 8) ^ swzV)];
          o[db] = mfma32(vf, pa[kf], o[db]);
        }
      }
      __builtin_amdgcn_s_setprio(0);
    }
    __syncthreads();   // Vs consumed -> next tile may overwrite
    cur ^= 1;
  }

  uint16_t* Yp = Y + ((size_t)(b * T + row0 + ql)) * 2048 + h * 128 + b5 * 4;
  const float inv = 1.f / lrow;
#pragma unroll
  for (int db = 0; db < 4; ++db)
#pragma unroll
    for (int a = 0; a < 4; ++a) {
      u16x4v pk;
#pragma unroll
      for (int r = 0; r < 4; ++r) pk[r] = f2bfn(o[db][4 * a + r] * inv);
      *(u16x4v*)&Yp[db * 32 + a * 8] = pk;
    }
}

extern "C" void kernel_launch(void* const* d_in, const int* in_sizes, int n_in,
                              void* d_out, int out_size, void* d_ws, size_t ws_size,
                              hipStream_t stream) {
  const float* x      = (const float*)d_in[0];
  const float* W_attn = (const float*)d_in[1];
  const float* b_attn = (const float*)d_in[2];
  const float* W_proj = (const float*)d_in[3];
  const float* b_proj = (const float*)d_in[4];
  float* out = (float*)d_out;

  const int B = 4, T = 2048, C = 2048, H = 16, HKV = 4, HS = 128;
  const int M = B * T;               // 8192
  const int Nqkv = C + 2 * HKV * HS; // 3072

  uint8_t* ws = (uint8_t*)d_ws;
  size_t off = 0;
  auto alloc = [&](size_t bytes) {
    void* p = ws + off;
    off += (bytes + 255) & ~(size_t)255;
    return p;
  };
  uint16_t* xb  = (uint16_t*)alloc((size_t)M * C * 2);      // reused as yb after qkv
  uint16_t* WaT = (uint16_t*)alloc((size_t)Nqkv * C * 2);
  uint16_t* WpT = (uint16_t*)alloc((size_t)C * C * 2);
  uint16_t* qb  = (uint16_t*)alloc((size_t)B * H * T * HS * 2);
  uint16_t* kb  = (uint16_t*)alloc((size_t)B * HKV * T * HS * 2);
  uint16_t* vtb = (uint16_t*)alloc((size_t)B * HKV * HS * T * 2);  // V^T direct
  uint16_t* yb  = xb;

  cvt_f32_bf16<<<2048, 256, 0, stream>>>(x, xb, M * C / 4);
  transp_cvt<<<dim3(Nqkv / 64, C / 64), 256, 0, stream>>>(W_attn, WaT, C, Nqkv);
  transp_cvt<<<dim3(C / 64, C / 64), 256, 0, stream>>>(W_proj, WpT, C, C);
  gemm_qkv<<<dim3((M / 256) * (Nqkv / 128)), 512, 0, stream>>>(
      xb, WaT, b_attn, qb, kb, vtb, M, Nqkv, C);
  attn_fwd<<<dim3(512), 512, 0, stream>>>(qb, kb, vtb, yb, T);
  gemm_proj<<<dim3((M / 256) * (C / 256)), 512, 0, stream>>>(
      yb, WpT, b_proj, out, M, C, C);
}

// Round 19
// 329.968 us; speedup vs baseline: 1.0294x; 1.0294x over previous
//
#include <hip/hip_runtime.h>
#include <stdint.h>

#define DEVI __device__ __forceinline__

typedef __attribute__((ext_vector_type(8))) uint16_t u16x8;
typedef __attribute__((ext_vector_type(4))) uint16_t u16x4v;
typedef __attribute__((ext_vector_type(4))) uint32_t u32x4;
typedef __attribute__((ext_vector_type(8))) __bf16 bf16x8;
typedef __attribute__((ext_vector_type(4))) float f32x4;
typedef __attribute__((ext_vector_type(16))) float f32x16;

DEVI uint16_t f2bf(float x) {
  union { float f; uint32_t u; } v; v.f = x;
  return (uint16_t)((v.u + 0x7fffu + ((v.u >> 16) & 1u)) >> 16);
}

DEVI uint16_t f2bfn(float f) {
  __bf16 h = (__bf16)f;
  return __builtin_bit_cast(uint16_t, h);
}

DEVI f32x4 mfma16(u16x8 a, u16x8 b, f32x4 c) {
  return __builtin_amdgcn_mfma_f32_16x16x32_bf16(
      __builtin_bit_cast(bf16x8, a), __builtin_bit_cast(bf16x8, b), c, 0, 0, 0);
}

DEVI f32x16 mfma32(u16x8 a, u16x8 b, f32x16 c) {
  return __builtin_amdgcn_mfma_f32_32x32x16_bf16(
      __builtin_bit_cast(bf16x8, a), __builtin_bit_cast(bf16x8, b), c, 0, 0, 0);
}

DEVI void async16(void* lds, const void* g) {
  __builtin_amdgcn_global_load_lds(
      (const __attribute__((address_space(1))) uint32_t*)g,
      (__attribute__((address_space(3))) uint32_t*)lds, 16, 0, 0);
}

// 1/sqrt(128) * log2(e): softmax computed in exp2 domain, scale folded into Q.
#define QSC 0.12751742925f

// ---------------- elementwise f32 -> bf16 ----------------
__global__ void cvt_f32_bf16(const float* __restrict__ in, uint16_t* __restrict__ out, int n4) {
  int i = blockIdx.x * blockDim.x + threadIdx.x;
  const int st = gridDim.x * blockDim.x;
  for (; i < n4; i += st) {
    float4 v = ((const float4*)in)[i];
    u16x4v o;
    o[0] = f2bf(v.x); o[1] = f2bf(v.y); o[2] = f2bf(v.z); o[3] = f2bf(v.w);
    ((u16x4v*)out)[i] = o;
  }
}

// ------------- transpose + convert: f32 [K][N] -> bf16 [N][K] -------------
__global__ void transp_cvt(const float* __restrict__ in, uint16_t* __restrict__ out,
                           int K, int N) {
  __shared__ float Ws[64][65];
  const int n0 = blockIdx.x * 64, k0 = blockIdx.y * 64;
  const int t = threadIdx.x;
  const int r = t >> 4, c = (t & 15) << 2;
#pragma unroll
  for (int it = 0; it < 4; ++it) {
    float4 v = *(const float4*)&in[(size_t)(k0 + it * 16 + r) * N + n0 + c];
    Ws[it * 16 + r][c] = v.x; Ws[it * 16 + r][c + 1] = v.y;
    Ws[it * 16 + r][c + 2] = v.z; Ws[it * 16 + r][c + 3] = v.w;
  }
  __syncthreads();
#pragma unroll
  for (int it = 0; it < 4; ++it) {
    const int rr = it * 16 + r;   // n index in tile
    const int cc = c;             // k index in tile
    ushort4 o;
    o.x = f2bf(Ws[cc][rr]);     o.y = f2bf(Ws[cc + 1][rr]);
    o.z = f2bf(Ws[cc + 2][rr]); o.w = f2bf(Ws[cc + 3][rr]);
    *(ushort4*)&out[(size_t)(n0 + rr) * K + k0 + cc] = o;
  }
}

// ------ qkv GEMM: 256x192 tile, 2-phase x 24-MFMA (round-19) ------
// Round-18's deep cover was null -> phase cost is the fixed skeleton
// (ds_read issue + 2 barriers + stage issue), NOT load latency. Lever:
// fewer phases per FLOP. BM=256, BN=192 -> grid 32x16 = 512 blocks =
// EXACTLY 2.0 rounds; 64 phases x 24 MFMA (vs 768 blocks x 64 x 16).
// Total phases 49152 -> 32768 (-33%). 8 waves (4M x 2N, per-wave 64x96).
// LDS = A dbuf 64K + B dbuf 48K = 112 KB. Pipeline = round-12 verified:
// p0 reads B(t) frags + A(t) half, issues A(t+1)->Abuf^1; p1 reads A(t)
// half2, issues B(t+2)->Bbuf[t&1] (dead space) + vmcnt(3) (newest 3 =
// B(t+2); proves A(t+1), B(t+1) landed). q/k/v boundaries (2048,2560)
// are 16-aligned -> every 16-wide fragment region-uniform.
// V^T fused epilogue (round-16 verified). T2 chunk swizzle both sides.
__global__ __launch_bounds__(512, 1)
void gemm_qkv(const uint16_t* __restrict__ A, const uint16_t* __restrict__ Bt,
              const float* __restrict__ bias,
              uint16_t* __restrict__ q, uint16_t* __restrict__ kk, uint16_t* __restrict__ vt,
              int M, int N, int K) {
  constexpr int BK = 64;
  __shared__ uint16_t As[2][256 * BK];   // 64 KB
  __shared__ uint16_t Bs[2][192 * BK];   // 48 KB
  int bid = (int)blockIdx.x;
  const int q8 = (int)gridDim.x >> 3;
  bid = (bid & 7) * q8 + (bid >> 3);
  const int nbn = N / 192;
  const int brow = (bid / nbn) << 8;
  const int bcol = (bid % nbn) * 192;
  const int t = threadIdx.x;
  const int wid = t >> 6, lane = t & 63;
  const int wm = wid >> 1, wn = wid & 1;          // 4 x 2 wave grid (64 x 96 per wave)
  const int lr = lane & 15, g = lane >> 4, l7 = lr & 7;

  const int logch = (((t & 7) ^ ((t >> 3) & 7)) << 3);
  const uint16_t* Asrc = A + (size_t)(brow + (t >> 3)) * K + logch;
  const uint16_t* Bsrc = Bt + (size_t)(bcol + (t >> 3)) * K + logch;
  const size_t skip64 = (size_t)64 * K;
  const int dt = t * 8;

  auto stageA = [&](int buf, int k0) {
#pragma unroll
    for (int l = 0; l < 4; ++l)
      async16(&As[buf][l * 4096 + dt], Asrc + (size_t)l * skip64 + k0);
  };
  auto stageB = [&](int buf, int k0) {
#pragma unroll
    for (int l = 0; l < 3; ++l)
      async16(&Bs[buf][l * 4096 + dt], Bsrc + (size_t)l * skip64 + k0);
  };

  f32x4 acc[4][6];
#pragma unroll
  for (int i = 0; i < 4; ++i)
#pragma unroll
    for (int j = 0; j < 6; ++j) acc[i][j] = f32x4{0.f, 0.f, 0.f, 0.f};

  const int nt = K / BK;
  stageA(0, 0); stageB(0, 0);
  if (nt > 1) stageB(1, BK);
  asm volatile("s_waitcnt vmcnt(0)" ::: "memory");
  __builtin_amdgcn_s_barrier();

  for (int tt = 0; tt < nt; ++tt) {
    const int buf = tt & 1;
    u16x8 bfr[6][2];
#pragma unroll
    for (int p = 0; p < 2; ++p) {
      if (p == 0) {
#pragma unroll
        for (int j = 0; j < 6; ++j) {
          const int brw = wn * 96 + j * 16 + lr;
#pragma unroll
          for (int s = 0; s < 2; ++s)
            bfr[j][s] = *(const u16x8*)&Bs[buf][brw * 64 + ((((s << 2) + g) ^ l7) << 3)];
        }
      }
      u16x8 af[2][2];
#pragma unroll
      for (int ii = 0; ii < 2; ++ii) {
        const int arow = wm * 64 + (p * 2 + ii) * 16 + lr;
#pragma unroll
        for (int s = 0; s < 2; ++s)
          af[ii][s] = *(const u16x8*)&As[buf][arow * 64 + ((((s << 2) + g) ^ l7) << 3)];
      }
      if (p == 0) {
        if (tt + 1 < nt) stageA(buf ^ 1, (tt + 1) * BK);
      } else {
        if (tt + 2 < nt) {
          stageB(buf, (tt + 2) * BK);
          asm volatile("s_waitcnt vmcnt(3)" ::: "memory");
        } else {
          asm volatile("s_waitcnt vmcnt(0)" ::: "memory");
        }
      }
      __builtin_amdgcn_s_barrier();
      __builtin_amdgcn_s_setprio(1);
#pragma unroll
      for (int ii = 0; ii < 2; ++ii)
#pragma unroll
        for (int j = 0; j < 6; ++j)
#pragma unroll
          for (int s = 0; s < 2; ++s)
            acc[p * 2 + ii][j] = mfma16(af[ii][s], bfr[j][s], acc[p * 2 + ii][j]);
      __builtin_amdgcn_s_setprio(0);
      __builtin_amdgcn_s_barrier();
    }
  }

#pragma unroll
  for (int i = 0; i < 4; ++i) {
#pragma unroll
    for (int j = 0; j < 6; ++j) {
      const int col = bcol + wn * 96 + j * 16 + lr;
      const float bb = bias[col];
      const int rowb = brow + wm * 64 + i * 16 + (g << 2);
      const int b_ = rowb >> 11, ttb = rowb & 2047;   // r-span stays in one seq
      const int d = col & 127;
      float vals[4];
#pragma unroll
      for (int r = 0; r < 4; ++r) vals[r] = acc[i][j][r] + bb;
      if (col < 2048) {
        const int hh = col >> 7;
#pragma unroll
        for (int r = 0; r < 4; ++r)
          q[((size_t)((b_ * 16 + hh) * 2048 + ttb + r) << 7) + d] = f2bf(vals[r] * QSC);
      } else if (col < 2560) {
        const int hh = (col - 2048) >> 7;
#pragma unroll
        for (int r = 0; r < 4; ++r)
          kk[((size_t)((b_ * 4 + hh) * 2048 + ttb + r) << 7) + d] = f2bf(vals[r]);
      } else {
        const int hh = (col - 2560) >> 7;
        u16x4v pk;
#pragma unroll
        for (int r = 0; r < 4; ++r) pk[r] = f2bf(vals[r]);
        *(u16x4v*)&vt[(((size_t)((b_ * 4 + hh) * 128 + d)) << 11) + ttb] = pk;
      }
    }
  }
}

// ------------- proj GEMM: 8-phase 256x256 schedule (round-11, verified) -----
__global__ __launch_bounds__(512, 1)
void gemm_proj(const uint16_t* __restrict__ A, const uint16_t* __restrict__ Bt,
               const float* __restrict__ bias, float* __restrict__ outF,
               int M, int N, int K) {
  constexpr int BK = 64;
  __shared__ uint16_t As[2][256 * BK];   // 64 KB
  __shared__ uint16_t Bs[2][256 * BK];   // 64 KB
  int bid = (int)blockIdx.x;
  const int q8 = (int)gridDim.x >> 3;
  bid = (bid & 7) * q8 + (bid >> 3);
  const int nbn = N >> 8;
  const int brow = (bid / nbn) << 8;
  const int bcol = (bid % nbn) << 8;
  const int t = threadIdx.x;
  const int wid = t >> 6, lane = t & 63;
  const int wm = wid >> 2, wn = wid & 3;          // 2 x 4 wave grid
  const int lr = lane & 15, g = lane >> 4;
  const int l7 = lr & 7;

  const int sr0 = t >> 3;
  const int logch = (((t & 7) ^ ((t >> 3) & 7)) << 3);
  const uint16_t* Asrc0 = A + (size_t)(brow + sr0) * K + logch;
  const uint16_t* Asrc1 = A + (size_t)(brow + 64 + sr0) * K + logch;
  const uint16_t* Bsrc0 = Bt + (size_t)(bcol + sr0) * K + logch;
  const uint16_t* Bsrc1 = Bt + (size_t)(bcol + 64 + sr0) * K + logch;
  const size_t hskip = (size_t)128 * K;
  const int d0 = t * 8, d1 = 4096 + t * 8;

  auto stageA = [&](int buf, int h, int k0) {
    async16(&As[buf][h * 8192 + d0], Asrc0 + (size_t)h * hskip + k0);
    async16(&As[buf][h * 8192 + d1], Asrc1 + (size_t)h * hskip + k0);
  };
  auto stageB = [&](int buf, int h, int k0) {
    async16(&Bs[buf][h * 8192 + d0], Bsrc0 + (size_t)h * hskip + k0);
    async16(&Bs[buf][h * 8192 + d1], Bsrc1 + (size_t)h * hskip + k0);
  };

  f32x4 acc[8][4];
#pragma unroll
  for (int i = 0; i < 8; ++i)
#pragma unroll
    for (int j = 0; j < 4; ++j) acc[i][j] = f32x4{0.f, 0.f, 0.f, 0.f};

  const int nt = K / BK;
  stageA(0, 0, 0); stageA(0, 1, 0);
  stageB(0, 0, 0); stageB(0, 1, 0);
  if (nt > 1) { stageB(1, 0, BK); stageB(1, 1, BK); }
  asm volatile("s_waitcnt vmcnt(0)" ::: "memory");
  __builtin_amdgcn_s_barrier();

  for (int tt = 0; tt < nt; ++tt) {
    const int buf = tt & 1;
    u16x8 bfr[4][2];
#pragma unroll
    for (int p = 0; p < 4; ++p) {
      if (p == 0) {
#pragma unroll
        for (int j = 0; j < 4; ++j) {
          const int brw = wn * 64 + j * 16 + lr;
#pragma unroll
          for (int s = 0; s < 2; ++s)
            bfr[j][s] = *(const u16x8*)&Bs[buf][brw * 64 + ((((s << 2) + g) ^ l7) << 3)];
        }
      }
      u16x8 af[2][2];
#pragma unroll
      for (int ii = 0; ii < 2; ++ii) {
        const int arow = wm * 128 + (p * 2 + ii) * 16 + lr;
#pragma unroll
        for (int s = 0; s < 2; ++s)
          af[ii][s] = *(const u16x8*)&As[buf][arow * 64 + ((((s << 2) + g) ^ l7) << 3)];
      }
      if (p == 0) { if (tt + 1 < nt) stageA(buf ^ 1, 0, (tt + 1) * BK); }
      if (p == 1) { if (tt + 1 < nt) stageA(buf ^ 1, 1, (tt + 1) * BK); }
      if (p == 2) { if (tt + 2 < nt) stageB(buf, 0, (tt + 2) * BK); }
      if (p == 3) {
        if (tt + 2 < nt) {
          stageB(buf, 1, (tt + 2) * BK);
          asm volatile("s_waitcnt vmcnt(4)" ::: "memory");
        } else {
          asm volatile("s_waitcnt vmcnt(0)" ::: "memory");
        }
      }
      __builtin_amdgcn_s_barrier();
      __builtin_amdgcn_s_setprio(1);
#pragma unroll
      for (int ii = 0; ii < 2; ++ii)
#pragma unroll
        for (int j = 0; j < 4; ++j)
#pragma unroll
          for (int s = 0; s < 2; ++s)
            acc[p * 2 + ii][j] = mfma16(af[ii][s], bfr[j][s], acc[p * 2 + ii][j]);
      __builtin_amdgcn_s_setprio(0);
      __builtin_amdgcn_s_barrier();
    }
  }

#pragma unroll
  for (int i = 0; i < 8; ++i) {
#pragma unroll
    for (int j = 0; j < 4; ++j) {
      const int col = bcol + wn * 64 + j * 16 + lr;
      const float bb = bias[col];
#pragma unroll
      for (int r = 0; r < 4; ++r) {
        const int row = brow + wm * 128 + i * 16 + (g << 2) + r;
        outF[(size_t)row * N + col] = acc[i][j][r] + bb;
      }
    }
  }
}

// ------------- flash attention (causal, GQA 4:1) -------------
// ROUND-15 attn verbatim (best verified: 137 us, 92 VGPR, no spill).
__global__ __launch_bounds__(512, 1)
void attn_fwd(const uint16_t* __restrict__ Q,   // [B*16][T][128], pre-scaled by QSC
              const uint16_t* __restrict__ Kg,  // [B*4][T][128]
              const uint16_t* __restrict__ Vt,  // [B*4][128][T]
              uint16_t* __restrict__ Y,         // [B*T][2048], col offset h*128
              int T) {
  __shared__ __align__(16) uint16_t Ks[2][64 * 128];   // 32 KB (dbuf)
  __shared__ __align__(16) uint16_t Vs[128 * 64];      // 16 KB (single)
  const int id = (int)blockIdx.x;
  const int x = id & 7;
  const int h = (id >> 3) & 15, b = (id >> 7) & 3;
  const int qb = (id & 256) ? 7 - x : x;      // complementary across bit 8
  const int hkv = h >> 2;

  const int t = threadIdx.x, w = t >> 6, lane = t & 63;
  const int ql = lane & 31, b5 = lane >> 5;
  const int swzK = (ql & 15) << 3;
  const int swzV = (ql & 7) << 3;

  const uint16_t* Qp = Q + ((size_t)(b * 16 + h) * T + qb * 256) * 128;
  const uint16_t* Kp = Kg + (size_t)(b * 4 + hkv) * T * 128;
  const uint16_t* Vp = Vt + (size_t)(b * 4 + hkv) * 128 * T;

  auto stageK = [&](int buf, int kv0) {
#pragma unroll
    for (int l = 0; l < 2; ++l) {
      const int s = l * 512 + t;
      const int row = s >> 4;                       // 0..63
      const int cl = (s & 15) ^ (row & 15);
      async16(&Ks[buf][s * 8], &Kp[(size_t)(kv0 + row) * 128 + cl * 8]);
    }
  };
  auto stageV = [&](int kv0) {
#pragma unroll
    for (int l = 0; l < 2; ++l) {
      const int s = l * 512 + t;
      const int row = s >> 3;                       // 0..127
      const int cl = (s & 7) ^ (row & 7);
      async16(&Vs[s * 8], &Vp[(size_t)row * T + kv0 + cl * 8]);
    }
  };

  const int row0 = qb * 256 + w * 32;
  const int qrow = row0 + ql;

  u16x8 qf[8];
#pragma unroll
  for (int kc = 0; kc < 8; ++kc)
    qf[kc] = *(const u16x8*)&Qp[(size_t)(w * 32 + ql) * 128 + kc * 16 + b5 * 8];

  f32x16 o[4];  // O^T: lane holds O[d=32db+(reg&3)+8(reg>>2)+4b5][q=ql]
#pragma unroll
  for (int db = 0; db < 4; ++db)
#pragma unroll
    for (int r = 0; r < 16; ++r) o[db][r] = 0.f;
  float mrow = -3e38f, lrow = 0.f;

  const int ntiles = 4 * qb + 4;
  const int myn = 4 * qb + (w >> 1) + 1;  // waves skip fully-masked tail tiles

  stageK(0, 0);
  __syncthreads();

  int cur = 0;
  for (int tile = 0; tile < ntiles; ++tile) {
    const int kv0 = tile << 6;
    stageV(kv0);
    if (tile + 1 < ntiles) stageK(cur ^ 1, (tile + 1) << 6);

    const bool run = tile < myn;
    f32x16 s[2];
    u16x8 pa[4];
    if (run) {
#pragma unroll
      for (int m = 0; m < 2; ++m)
#pragma unroll
        for (int r = 0; r < 16; ++r) s[m][r] = 0.f;
      __builtin_amdgcn_s_setprio(1);
#pragma unroll
      for (int kc = 0; kc < 8; ++kc) {
        const int cc = (kc * 16 + b5 * 8) ^ swzK;
        u16x8 k0f = *(const u16x8*)&Ks[cur][ql * 128 + cc];
        u16x8 k1f = *(const u16x8*)&Ks[cur][(32 + ql) * 128 + cc];
        s[0] = mfma32(k0f, qf[kc], s[0]);
        s[1] = mfma32(k1f, qf[kc], s[1]);
      }
      __builtin_amdgcn_s_setprio(0);

      // causal mask
      if (kv0 + 63 > row0) {
#pragma unroll
        for (int m = 0; m < 2; ++m)
#pragma unroll
          for (int r = 0; r < 16; ++r) {
            const int kg = kv0 + 32 * m + (r & 3) + 8 * (r >> 2) + 4 * b5;
            if (kg > qrow) s[m][r] = -3e38f;
          }
      }
      // online softmax: tree max (dep depth 5)
      float mt[16];
#pragma unroll
      for (int r = 0; r < 16; ++r) mt[r] = fmaxf(s[0][r], s[1][r]);
#pragma unroll
      for (int st = 8; st >= 1; st >>= 1)
#pragma unroll
        for (int r = 0; r < st; ++r) mt[r] = fmaxf(mt[r], mt[r + st]);
      float mx = fmaxf(mt[0], __shfl_xor(mt[0], 32));
      // defer-max (THR=8)
      const bool defer = __all(mx <= mrow + 8.f);
      const float mnew = defer ? mrow : fmaxf(mrow, mx);
      const float sc = defer ? 1.f : exp2f(mrow - mnew);
#pragma unroll
      for (int m = 0; m < 2; ++m)
#pragma unroll
        for (int r = 0; r < 16; ++r) s[m][r] = exp2f(s[m][r] - mnew);
      // tree sum (dep depth 5)
      float pt[16];
#pragma unroll
      for (int r = 0; r < 16; ++r) pt[r] = s[0][r] + s[1][r];
#pragma unroll
      for (int st = 8; st >= 1; st >>= 1)
#pragma unroll
        for (int r = 0; r < st; ++r) pt[r] += pt[r + st];
      float ps = pt[0] + __shfl_xor(pt[0], 32);
      mrow = mnew;
      lrow = lrow * sc + ps;
      if (!defer) {
#pragma unroll
        for (int db = 0; db < 4; ++db)
#pragma unroll
          for (int r = 0; r < 16; ++r) o[db][r] *= sc;
      }

      // P -> B-operand fragments, fully in-register (cross-b5 exchange only)
#pragma unroll
      for (int m = 0; m < 2; ++m) {
        uint32_t pw[4][2];
#pragma unroll
        for (int a = 0; a < 4; ++a)
#pragma unroll
          for (int hh = 0; hh < 2; ++hh)
            pw[a][hh] = (uint32_t)f2bfn(s[m][4 * a + 2 * hh]) |
                        ((uint32_t)f2bfn(s[m][4 * a + 2 * hh + 1]) << 16);
#pragma unroll
        for (int c = 0; c < 2; ++c) {
          uint32_t wd[4];
#pragma unroll
          for (int hh = 0; hh < 2; ++hh) {
            const uint32_t mine  = b5 ? pw[2 * c + 1][hh] : pw[2 * c][hh];
            const uint32_t yours = b5 ? pw[2 * c][hh] : pw[2 * c + 1][hh];
            const uint32_t xw = (uint32_t)__shfl_xor((int)yours, 32);
            wd[hh] = b5 ? xw : mine;
            wd[2 + hh] = b5 ? mine : xw;
          }
          u32x4 tmp = {wd[0], wd[1], wd[2], wd[3]};
          pa[2 * m + c] = __builtin_bit_cast(u16x8, tmp);
        }
      }
    }
    __syncthreads();   // drains V(t) (+K(t+1)); all QK reads of Ks[cur] done

    if (run) {
      __builtin_amdgcn_s_setprio(1);
#pragma unroll
      for (int db = 0; db < 4; ++db) {
#pragma unroll
        for (int kf = 0; kf < 4; ++kf) {
          u16x8 vf = *(const u16x8*)&Vs[(32 * db + ql) * 64 +
                                        ((kf * 16 + b5 * 8) ^ swzV)];
          o[db] = mfma32(vf, pa[kf], o[db]);
        }
      }
      __builtin_amdgcn_s_setprio(0);
    }
    __syncthreads();   // Vs consumed -> next tile may overwrite
    cur ^= 1;
  }

  uint16_t* Yp = Y + ((size_t)(b * T + row0 + ql)) * 2048 + h * 128 + b5 * 4;
  const float inv = 1.f / lrow;
#pragma unroll
  for (int db = 0; db < 4; ++db)
#pragma unroll
    for (int a = 0; a < 4; ++a) {
      u16x4v pk;
#pragma unroll
      for (int r = 0; r < 4; ++r) pk[r] = f2bfn(o[db][4 * a + r] * inv);
      *(u16x4v*)&Yp[db * 32 + a * 8] = pk;
    }
}

extern "C" void kernel_launch(void* const* d_in, const int* in_sizes, int n_in,
                              void* d_out, int out_size, void* d_ws, size_t ws_size,
                              hipStream_t stream) {
  const float* x      = (const float*)d_in[0];
  const float* W_attn = (const float*)d_in[1];
  const float* b_attn = (const float*)d_in[2];
  const float* W_proj = (const float*)d_in[3];
  const float* b_proj = (const float*)d_in[4];
  float* out = (float*)d_out;

  const int B = 4, T = 2048, C = 2048, H = 16, HKV = 4, HS = 128;
  const int M = B * T;               // 8192
  const int Nqkv = C + 2 * HKV * HS; // 3072

  uint8_t* ws = (uint8_t*)d_ws;
  size_t off = 0;
  auto alloc = [&](size_t bytes) {
    void* p = ws + off;
    off += (bytes + 255) & ~(size_t)255;
    return p;
  };
  uint16_t* xb  = (uint16_t*)alloc((size_t)M * C * 2);      // reused as yb after qkv
  uint16_t* WaT = (uint16_t*)alloc((size_t)Nqkv * C * 2);
  uint16_t* WpT = (uint16_t*)alloc((size_t)C * C * 2);
  uint16_t* qb  = (uint16_t*)alloc((size_t)B * H * T * HS * 2);
  uint16_t* kb  = (uint16_t*)alloc((size_t)B * HKV * T * HS * 2);
  uint16_t* vtb = (uint16_t*)alloc((size_t)B * HKV * HS * T * 2);  // V^T direct
  uint16_t* yb  = xb;

  cvt_f32_bf16<<<2048, 256, 0, stream>>>(x, xb, M * C / 4);
  transp_cvt<<<dim3(Nqkv / 64, C / 64), 256, 0, stream>>>(W_attn, WaT, C, Nqkv);
  transp_cvt<<<dim3(C / 64, C / 64), 256, 0, stream>>>(W_proj, WpT, C, C);
  gemm_qkv<<<dim3((M / 256) * (Nqkv / 192)), 512, 0, stream>>>(
      xb, WaT, b_attn, qb, kb, vtb, M, Nqkv, C);
  attn_fwd<<<dim3(512), 512, 0, stream>>>(qb, kb, vtb, yb, T);
  gemm_proj<<<dim3((M / 256) * (C / 256)), 512, 0, stream>>>(
      yb, WpT, b_proj, out, M, C, C);
}

// Round 20
// 319.686 us; speedup vs baseline: 1.0625x; 1.0322x over previous
//
#include <hip/hip_runtime.h>
#include <stdint.h>

#define DEVI __device__ __forceinline__

typedef __attribute__((ext_vector_type(8))) uint16_t u16x8;
typedef __attribute__((ext_vector_type(4))) uint16_t u16x4v;
typedef __attribute__((ext_vector_type(4))) uint32_t u32x4;
typedef __attribute__((ext_vector_type(8))) __bf16 bf16x8;
typedef __attribute__((ext_vector_type(4))) float f32x4;
typedef __attribute__((ext_vector_type(16))) float f32x16;

DEVI uint16_t f2bf(float x) {
  union { float f; uint32_t u; } v; v.f = x;
  return (uint16_t)((v.u + 0x7fffu + ((v.u >> 16) & 1u)) >> 16);
}

DEVI uint16_t f2bfn(float f) {
  __bf16 h = (__bf16)f;
  return __builtin_bit_cast(uint16_t, h);
}

DEVI f32x4 mfma16(u16x8 a, u16x8 b, f32x4 c) {
  return __builtin_amdgcn_mfma_f32_16x16x32_bf16(
      __builtin_bit_cast(bf16x8, a), __builtin_bit_cast(bf16x8, b), c, 0, 0, 0);
}

DEVI f32x16 mfma32(u16x8 a, u16x8 b, f32x16 c) {
  return __builtin_amdgcn_mfma_f32_32x32x16_bf16(
      __builtin_bit_cast(bf16x8, a), __builtin_bit_cast(bf16x8, b), c, 0, 0, 0);
}

DEVI void async16(void* lds, const void* g) {
  __builtin_amdgcn_global_load_lds(
      (const __attribute__((address_space(1))) uint32_t*)g,
      (__attribute__((address_space(3))) uint32_t*)lds, 16, 0, 0);
}

// 1/sqrt(128) * log2(e): softmax computed in exp2 domain, scale folded into Q.
#define QSC 0.12751742925f

// ---------------- elementwise f32 -> bf16 ----------------
__global__ void cvt_f32_bf16(const float* __restrict__ in, uint16_t* __restrict__ out, int n4) {
  int i = blockIdx.x * blockDim.x + threadIdx.x;
  const int st = gridDim.x * blockDim.x;
  for (; i < n4; i += st) {
    float4 v = ((const float4*)in)[i];
    u16x4v o;
    o[0] = f2bf(v.x); o[1] = f2bf(v.y); o[2] = f2bf(v.z); o[3] = f2bf(v.w);
    ((u16x4v*)out)[i] = o;
  }
}

// ------------- transpose + convert: f32 [K][N] -> bf16 [N][K] -------------
__global__ void transp_cvt(const float* __restrict__ in, uint16_t* __restrict__ out,
                           int K, int N) {
  __shared__ float Ws[64][65];
  const int n0 = blockIdx.x * 64, k0 = blockIdx.y * 64;
  const int t = threadIdx.x;
  const int r = t >> 4, c = (t & 15) << 2;
#pragma unroll
  for (int it = 0; it < 4; ++it) {
    float4 v = *(const float4*)&in[(size_t)(k0 + it * 16 + r) * N + n0 + c];
    Ws[it * 16 + r][c] = v.x; Ws[it * 16 + r][c + 1] = v.y;
    Ws[it * 16 + r][c + 2] = v.z; Ws[it * 16 + r][c + 3] = v.w;
  }
  __syncthreads();
#pragma unroll
  for (int it = 0; it < 4; ++it) {
    const int rr = it * 16 + r;   // n index in tile
    const int cc = c;             // k index in tile
    ushort4 o;
    o.x = f2bf(Ws[cc][rr]);     o.y = f2bf(Ws[cc + 1][rr]);
    o.z = f2bf(Ws[cc + 2][rr]); o.w = f2bf(Ws[cc + 3][rr]);
    *(ushort4*)&out[(size_t)(n0 + rr) * K + k0 + cc] = o;
  }
}

// ------ qkv GEMM: 256x192 tile, 2-phase x 24-MFMA (round-19, verified) ------
__global__ __launch_bounds__(512, 1)
void gemm_qkv(const uint16_t* __restrict__ A, const uint16_t* __restrict__ Bt,
              const float* __restrict__ bias,
              uint16_t* __restrict__ q, uint16_t* __restrict__ kk, uint16_t* __restrict__ vt,
              int M, int N, int K) {
  constexpr int BK = 64;
  __shared__ uint16_t As[2][256 * BK];   // 64 KB
  __shared__ uint16_t Bs[2][192 * BK];   // 48 KB
  int bid = (int)blockIdx.x;
  const int q8 = (int)gridDim.x >> 3;
  bid = (bid & 7) * q8 + (bid >> 3);
  const int nbn = N / 192;
  const int brow = (bid / nbn) << 8;
  const int bcol = (bid % nbn) * 192;
  const int t = threadIdx.x;
  const int wid = t >> 6, lane = t & 63;
  const int wm = wid >> 1, wn = wid & 1;          // 4 x 2 wave grid (64 x 96 per wave)
  const int lr = lane & 15, g = lane >> 4, l7 = lr & 7;

  const int logch = (((t & 7) ^ ((t >> 3) & 7)) << 3);
  const uint16_t* Asrc = A + (size_t)(brow + (t >> 3)) * K + logch;
  const uint16_t* Bsrc = Bt + (size_t)(bcol + (t >> 3)) * K + logch;
  const size_t skip64 = (size_t)64 * K;
  const int dt = t * 8;

  auto stageA = [&](int buf, int k0) {
#pragma unroll
    for (int l = 0; l < 4; ++l)
      async16(&As[buf][l * 4096 + dt], Asrc + (size_t)l * skip64 + k0);
  };
  auto stageB = [&](int buf, int k0) {
#pragma unroll
    for (int l = 0; l < 3; ++l)
      async16(&Bs[buf][l * 4096 + dt], Bsrc + (size_t)l * skip64 + k0);
  };

  f32x4 acc[4][6];
#pragma unroll
  for (int i = 0; i < 4; ++i)
#pragma unroll
    for (int j = 0; j < 6; ++j) acc[i][j] = f32x4{0.f, 0.f, 0.f, 0.f};

  const int nt = K / BK;
  stageA(0, 0); stageB(0, 0);
  if (nt > 1) stageB(1, BK);
  asm volatile("s_waitcnt vmcnt(0)" ::: "memory");
  __builtin_amdgcn_s_barrier();

  for (int tt = 0; tt < nt; ++tt) {
    const int buf = tt & 1;
    u16x8 bfr[6][2];
#pragma unroll
    for (int p = 0; p < 2; ++p) {
      if (p == 0) {
#pragma unroll
        for (int j = 0; j < 6; ++j) {
          const int brw = wn * 96 + j * 16 + lr;
#pragma unroll
          for (int s = 0; s < 2; ++s)
            bfr[j][s] = *(const u16x8*)&Bs[buf][brw * 64 + ((((s << 2) + g) ^ l7) << 3)];
        }
      }
      u16x8 af[2][2];
#pragma unroll
      for (int ii = 0; ii < 2; ++ii) {
        const int arow = wm * 64 + (p * 2 + ii) * 16 + lr;
#pragma unroll
        for (int s = 0; s < 2; ++s)
          af[ii][s] = *(const u16x8*)&As[buf][arow * 64 + ((((s << 2) + g) ^ l7) << 3)];
      }
      if (p == 0) {
        if (tt + 1 < nt) stageA(buf ^ 1, (tt + 1) * BK);
      } else {
        if (tt + 2 < nt) {
          stageB(buf, (tt + 2) * BK);
          asm volatile("s_waitcnt vmcnt(3)" ::: "memory");
        } else {
          asm volatile("s_waitcnt vmcnt(0)" ::: "memory");
        }
      }
      __builtin_amdgcn_s_barrier();
      __builtin_amdgcn_s_setprio(1);
#pragma unroll
      for (int ii = 0; ii < 2; ++ii)
#pragma unroll
        for (int j = 0; j < 6; ++j)
#pragma unroll
          for (int s = 0; s < 2; ++s)
            acc[p * 2 + ii][j] = mfma16(af[ii][s], bfr[j][s], acc[p * 2 + ii][j]);
      __builtin_amdgcn_s_setprio(0);
      __builtin_amdgcn_s_barrier();
    }
  }

#pragma unroll
  for (int i = 0; i < 4; ++i) {
#pragma unroll
    for (int j = 0; j < 6; ++j) {
      const int col = bcol + wn * 96 + j * 16 + lr;
      const float bb = bias[col];
      const int rowb = brow + wm * 64 + i * 16 + (g << 2);
      const int b_ = rowb >> 11, ttb = rowb & 2047;   // r-span stays in one seq
      const int d = col & 127;
      float vals[4];
#pragma unroll
      for (int r = 0; r < 4; ++r) vals[r] = acc[i][j][r] + bb;
      if (col < 2048) {
        const int hh = col >> 7;
#pragma unroll
        for (int r = 0; r < 4; ++r)
          q[((size_t)((b_ * 16 + hh) * 2048 + ttb + r) << 7) + d] = f2bf(vals[r] * QSC);
      } else if (col < 2560) {
        const int hh = (col - 2048) >> 7;
#pragma unroll
        for (int r = 0; r < 4; ++r)
          kk[((size_t)((b_ * 4 + hh) * 2048 + ttb + r) << 7) + d] = f2bf(vals[r]);
      } else {
        const int hh = (col - 2560) >> 7;
        u16x4v pk;
#pragma unroll
        for (int r = 0; r < 4; ++r) pk[r] = f2bf(vals[r]);
        *(u16x4v*)&vt[(((size_t)((b_ * 4 + hh) * 128 + d)) << 11) + ttb] = pk;
      }
    }
  }
}

// ------ proj GEMM: 256x256, 2-phase x 32-MFMA (round-20) ------
// Round-19 proved GEMM time ~ (phase count) x (fixed skeleton ~1030-1200cyc):
// deep-cover null (r18), density win (r19). proj moves 4ph x 16 MFMA ->
// 2ph x 32 MFMA: p0 = all B(t) frags + A rows 0..63, 32 MFMA; p1 = A rows
// 64..127, 32 MFMA. Staging/invariants identical in form to r12/r19: A(t+1)
// (4 glds) in p0 -> proven landed by p1's vmcnt(4); B(t+2) (4 glds) in p1
// into B(t)'s dead space; vmcnt(4) = newest 4 (B(t+2)) may fly. VGPR ~215
// (acc 128 + bfr 32 + af 32) < 256 cap at (512,1).
__global__ __launch_bounds__(512, 1)
void gemm_proj(const uint16_t* __restrict__ A, const uint16_t* __restrict__ Bt,
               const float* __restrict__ bias, float* __restrict__ outF,
               int M, int N, int K) {
  constexpr int BK = 64;
  __shared__ uint16_t As[2][256 * BK];   // 64 KB
  __shared__ uint16_t Bs[2][256 * BK];   // 64 KB
  int bid = (int)blockIdx.x;
  const int q8 = (int)gridDim.x >> 3;
  bid = (bid & 7) * q8 + (bid >> 3);
  const int nbn = N >> 8;
  const int brow = (bid / nbn) << 8;
  const int bcol = (bid % nbn) << 8;
  const int t = threadIdx.x;
  const int wid = t >> 6, lane = t & 63;
  const int wm = wid >> 2, wn = wid & 3;          // 2 x 4 wave grid
  const int lr = lane & 15, g = lane >> 4;
  const int l7 = lr & 7;

  const int sr0 = t >> 3;
  const int logch = (((t & 7) ^ ((t >> 3) & 7)) << 3);
  const uint16_t* Asrc0 = A + (size_t)(brow + sr0) * K + logch;
  const uint16_t* Asrc1 = A + (size_t)(brow + 64 + sr0) * K + logch;
  const uint16_t* Bsrc0 = Bt + (size_t)(bcol + sr0) * K + logch;
  const uint16_t* Bsrc1 = Bt + (size_t)(bcol + 64 + sr0) * K + logch;
  const size_t hskip = (size_t)128 * K;
  const int d0 = t * 8, d1 = 4096 + t * 8;

  auto stageA = [&](int buf, int k0) {
    async16(&As[buf][d0], Asrc0 + k0);
    async16(&As[buf][d1], Asrc1 + k0);
    async16(&As[buf][8192 + d0], Asrc0 + hskip + k0);
    async16(&As[buf][8192 + d1], Asrc1 + hskip + k0);
  };
  auto stageB = [&](int buf, int k0) {
    async16(&Bs[buf][d0], Bsrc0 + k0);
    async16(&Bs[buf][d1], Bsrc1 + k0);
    async16(&Bs[buf][8192 + d0], Bsrc0 + hskip + k0);
    async16(&Bs[buf][8192 + d1], Bsrc1 + hskip + k0);
  };

  f32x4 acc[8][4];
#pragma unroll
  for (int i = 0; i < 8; ++i)
#pragma unroll
    for (int j = 0; j < 4; ++j) acc[i][j] = f32x4{0.f, 0.f, 0.f, 0.f};

  const int nt = K / BK;
  stageA(0, 0); stageB(0, 0);
  if (nt > 1) stageB(1, BK);
  asm volatile("s_waitcnt vmcnt(0)" ::: "memory");
  __builtin_amdgcn_s_barrier();

  for (int tt = 0; tt < nt; ++tt) {
    const int buf = tt & 1;
    u16x8 bfr[4][2];
#pragma unroll
    for (int p = 0; p < 2; ++p) {
      if (p == 0) {
#pragma unroll
        for (int j = 0; j < 4; ++j) {
          const int brw = wn * 64 + j * 16 + lr;
#pragma unroll
          for (int s = 0; s < 2; ++s)
            bfr[j][s] = *(const u16x8*)&Bs[buf][brw * 64 + ((((s << 2) + g) ^ l7) << 3)];
        }
      }
      u16x8 af[4][2];
#pragma unroll
      for (int ii = 0; ii < 4; ++ii) {
        const int arow = wm * 128 + (p * 4 + ii) * 16 + lr;
#pragma unroll
        for (int s = 0; s < 2; ++s)
          af[ii][s] = *(const u16x8*)&As[buf][arow * 64 + ((((s << 2) + g) ^ l7) << 3)];
      }
      if (p == 0) {
        if (tt + 1 < nt) stageA(buf ^ 1, (tt + 1) * BK);
      } else {
        if (tt + 2 < nt) {
          stageB(buf, (tt + 2) * BK);
          asm volatile("s_waitcnt vmcnt(4)" ::: "memory");
        } else {
          asm volatile("s_waitcnt vmcnt(0)" ::: "memory");
        }
      }
      __builtin_amdgcn_s_barrier();
      __builtin_amdgcn_s_setprio(1);
#pragma unroll
      for (int ii = 0; ii < 4; ++ii)
#pragma unroll
        for (int j = 0; j < 4; ++j)
#pragma unroll
          for (int s = 0; s < 2; ++s)
            acc[p * 4 + ii][j] = mfma16(af[ii][s], bfr[j][s], acc[p * 4 + ii][j]);
      __builtin_amdgcn_s_setprio(0);
      __builtin_amdgcn_s_barrier();
    }
  }

#pragma unroll
  for (int i = 0; i < 8; ++i) {
#pragma unroll
    for (int j = 0; j < 4; ++j) {
      const int col = bcol + wn * 64 + j * 16 + lr;
      const float bb = bias[col];
#pragma unroll
      for (int r = 0; r < 4; ++r) {
        const int row = brow + wm * 128 + i * 16 + (g << 2) + r;
        outF[(size_t)row * N + col] = acc[i][j][r] + bb;
      }
    }
  }
}

// ------------- flash attention (causal, GQA 4:1) -------------
// ROUND-15 attn verbatim (best verified: 137 us, 92 VGPR, no spill).
__global__ __launch_bounds__(512, 1)
void attn_fwd(const uint16_t* __restrict__ Q,   // [B*16][T][128], pre-scaled by QSC
              const uint16_t* __restrict__ Kg,  // [B*4][T][128]
              const uint16_t* __restrict__ Vt,  // [B*4][128][T]
              uint16_t* __restrict__ Y,         // [B*T][2048], col offset h*128
              int T) {
  __shared__ __align__(16) uint16_t Ks[2][64 * 128];   // 32 KB (dbuf)
  __shared__ __align__(16) uint16_t Vs[128 * 64];      // 16 KB (single)
  const int id = (int)blockIdx.x;
  const int x = id & 7;
  const int h = (id >> 3) & 15, b = (id >> 7) & 3;
  const int qb = (id & 256) ? 7 - x : x;      // complementary across bit 8
  const int hkv = h >> 2;

  const int t = threadIdx.x, w = t >> 6, lane = t & 63;
  const int ql = lane & 31, b5 = lane >> 5;
  const int swzK = (ql & 15) << 3;
  const int swzV = (ql & 7) << 3;

  const uint16_t* Qp = Q + ((size_t)(b * 16 + h) * T + qb * 256) * 128;
  const uint16_t* Kp = Kg + (size_t)(b * 4 + hkv) * T * 128;
  const uint16_t* Vp = Vt + (size_t)(b * 4 + hkv) * 128 * T;

  auto stageK = [&](int buf, int kv0) {
#pragma unroll
    for (int l = 0; l < 2; ++l) {
      const int s = l * 512 + t;
      const int row = s >> 4;                       // 0..63
      const int cl = (s & 15) ^ (row & 15);
      async16(&Ks[buf][s * 8], &Kp[(size_t)(kv0 + row) * 128 + cl * 8]);
    }
  };
  auto stageV = [&](int kv0) {
#pragma unroll
    for (int l = 0; l < 2; ++l) {
      const int s = l * 512 + t;
      const int row = s >> 3;                       // 0..127
      const int cl = (s & 7) ^ (row & 7);
      async16(&Vs[s * 8], &Vp[(size_t)row * T + kv0 + cl * 8]);
    }
  };

  const int row0 = qb * 256 + w * 32;
  const int qrow = row0 + ql;

  u16x8 qf[8];
#pragma unroll
  for (int kc = 0; kc < 8; ++kc)
    qf[kc] = *(const u16x8*)&Qp[(size_t)(w * 32 + ql) * 128 + kc * 16 + b5 * 8];

  f32x16 o[4];  // O^T: lane holds O[d=32db+(reg&3)+8(reg>>2)+4b5][q=ql]
#pragma unroll
  for (int db = 0; db < 4; ++db)
#pragma unroll
    for (int r = 0; r < 16; ++r) o[db][r] = 0.f;
  float mrow = -3e38f, lrow = 0.f;

  const int ntiles = 4 * qb + 4;
  const int myn = 4 * qb + (w >> 1) + 1;  // waves skip fully-masked tail tiles

  stageK(0, 0);
  __syncthreads();

  int cur = 0;
  for (int tile = 0; tile < ntiles; ++tile) {
    const int kv0 = tile << 6;
    stageV(kv0);
    if (tile + 1 < ntiles) stageK(cur ^ 1, (tile + 1) << 6);

    const bool run = tile < myn;
    f32x16 s[2];
    u16x8 pa[4];
    if (run) {
#pragma unroll
      for (int m = 0; m < 2; ++m)
#pragma unroll
        for (int r = 0; r < 16; ++r) s[m][r] = 0.f;
      __builtin_amdgcn_s_setprio(1);
#pragma unroll
      for (int kc = 0; kc < 8; ++kc) {
        const int cc = (kc * 16 + b5 * 8) ^ swzK;
        u16x8 k0f = *(const u16x8*)&Ks[cur][ql * 128 + cc];
        u16x8 k1f = *(const u16x8*)&Ks[cur][(32 + ql) * 128 + cc];
        s[0] = mfma32(k0f, qf[kc], s[0]);
        s[1] = mfma32(k1f, qf[kc], s[1]);
      }
      __builtin_amdgcn_s_setprio(0);

      // causal mask
      if (kv0 + 63 > row0) {
#pragma unroll
        for (int m = 0; m < 2; ++m)
#pragma unroll
          for (int r = 0; r < 16; ++r) {
            const int kg = kv0 + 32 * m + (r & 3) + 8 * (r >> 2) + 4 * b5;
            if (kg > qrow) s[m][r] = -3e38f;
          }
      }
      // online softmax: tree max (dep depth 5)
      float mt[16];
#pragma unroll
      for (int r = 0; r < 16; ++r) mt[r] = fmaxf(s[0][r], s[1][r]);
#pragma unroll
      for (int st = 8; st >= 1; st >>= 1)
#pragma unroll
        for (int r = 0; r < st; ++r) mt[r] = fmaxf(mt[r], mt[r + st]);
      float mx = fmaxf(mt[0], __shfl_xor(mt[0], 32));
      // defer-max (THR=8)
      const bool defer = __all(mx <= mrow + 8.f);
      const float mnew = defer ? mrow : fmaxf(mrow, mx);
      const float sc = defer ? 1.f : exp2f(mrow - mnew);
#pragma unroll
      for (int m = 0; m < 2; ++m)
#pragma unroll
        for (int r = 0; r < 16; ++r) s[m][r] = exp2f(s[m][r] - mnew);
      // tree sum (dep depth 5)
      float pt[16];
#pragma unroll
      for (int r = 0; r < 16; ++r) pt[r] = s[0][r] + s[1][r];
#pragma unroll
      for (int st = 8; st >= 1; st >>= 1)
#pragma unroll
        for (int r = 0; r < st; ++r) pt[r] += pt[r + st];
      float ps = pt[0] + __shfl_xor(pt[0], 32);
      mrow = mnew;
      lrow = lrow * sc + ps;
      if (!defer) {
#pragma unroll
        for (int db = 0; db < 4; ++db)
#pragma unroll
          for (int r = 0; r < 16; ++r) o[db][r] *= sc;
      }

      // P -> B-operand fragments, fully in-register (cross-b5 exchange only)
#pragma unroll
      for (int m = 0; m < 2; ++m) {
        uint32_t pw[4][2];
#pragma unroll
        for (int a = 0; a < 4; ++a)
#pragma unroll
          for (int hh = 0; hh < 2; ++hh)
            pw[a][hh] = (uint32_t)f2bfn(s[m][4 * a + 2 * hh]) |
                        ((uint32_t)f2bfn(s[m][4 * a + 2 * hh + 1]) << 16);
#pragma unroll
        for (int c = 0; c < 2; ++c) {
          uint32_t wd[4];
#pragma unroll
          for (int hh = 0; hh < 2; ++hh) {
            const uint32_t mine  = b5 ? pw[2 * c + 1][hh] : pw[2 * c][hh];
            const uint32_t yours = b5 ? pw[2 * c][hh] : pw[2 * c + 1][hh];
            const uint32_t xw = (uint32_t)__shfl_xor((int)yours, 32);
            wd[hh] = b5 ? xw : mine;
            wd[2 + hh] = b5 ? mine : xw;
          }
          u32x4 tmp = {wd[0], wd[1], wd[2], wd[3]};
          pa[2 * m + c] = __builtin_bit_cast(u16x8, tmp);
        }
      }
    }
    __syncthreads();   // drains V(t) (+K(t+1)); all QK reads of Ks[cur] done

    if (run) {
      __builtin_amdgcn_s_setprio(1);
#pragma unroll
      for (int db = 0; db < 4; ++db) {
#pragma unroll
        for (int kf = 0; kf < 4; ++kf) {
          u16x8 vf = *(const u16x8*)&Vs[(32 * db + ql) * 64 +
                                        ((kf * 16 + b5 * 8) ^ swzV)];
          o[db] = mfma32(vf, pa[kf], o[db]);
        }
      }
      __builtin_amdgcn_s_setprio(0);
    }
    __syncthreads();   // Vs consumed -> next tile may overwrite
    cur ^= 1;
  }

  uint16_t* Yp = Y + ((size_t)(b * T + row0 + ql)) * 2048 + h * 128 + b5 * 4;
  const float inv = 1.f / lrow;
#pragma unroll
  for (int db = 0; db < 4; ++db)
#pragma unroll
    for (int a = 0; a < 4; ++a) {
      u16x4v pk;
#pragma unroll
      for (int r = 0; r < 4; ++r) pk[r] = f2bfn(o[db][4 * a + r] * inv);
      *(u16x4v*)&Yp[db * 32 + a * 8] = pk;
    }
}

extern "C" void kernel_launch(void* const* d_in, const int* in_sizes, int n_in,
                              void* d_out, int out_size, void* d_ws, size_t ws_size,
                              hipStream_t stream) {
  const float* x      = (const float*)d_in[0];
  const float* W_attn = (const float*)d_in[1];
  const float* b_attn = (const float*)d_in[2];
  const float* W_proj = (const float*)d_in[3];
  const float* b_proj = (const float*)d_in[4];
  float* out = (float*)d_out;

  const int B = 4, T = 2048, C = 2048, H = 16, HKV = 4, HS = 128;
  const int M = B * T;               // 8192
  const int Nqkv = C + 2 * HKV * HS; // 3072

  uint8_t* ws = (uint8_t*)d_ws;
  size_t off = 0;
  auto alloc = [&](size_t bytes) {
    void* p = ws + off;
    off += (bytes + 255) & ~(size_t)255;
    return p;
  };
  uint16_t* xb  = (uint16_t*)alloc((size_t)M * C * 2);      // reused as yb after qkv
  uint16_t* WaT = (uint16_t*)alloc((size_t)Nqkv * C * 2);
  uint16_t* WpT = (uint16_t*)alloc((size_t)C * C * 2);
  uint16_t* qb  = (uint16_t*)alloc((size_t)B * H * T * HS * 2);
  uint16_t* kb  = (uint16_t*)alloc((size_t)B * HKV * T * HS * 2);
  uint16_t* vtb = (uint16_t*)alloc((size_t)B * HKV * HS * T * 2);  // V^T direct
  uint16_t* yb  = xb;

  cvt_f32_bf16<<<2048, 256, 0, stream>>>(x, xb, M * C / 4);
  transp_cvt<<<dim3(Nqkv / 64, C / 64), 256, 0, stream>>>(W_attn, WaT, C, Nqkv);
  transp_cvt<<<dim3(C / 64, C / 64), 256, 0, stream>>>(W_proj, WpT, C, C);
  gemm_qkv<<<dim3((M / 256) * (Nqkv / 192)), 512, 0, stream>>>(
      xb, WaT, b_attn, qb, kb, vtb, M, Nqkv, C);
  attn_fwd<<<dim3(512), 512, 0, stream>>>(qb, kb, vtb, yb, T);
  gemm_proj<<<dim3((M / 256) * (C / 256)), 512, 0, stream>>>(
      yb, WpT, b_proj, out, M, C, C);
}

// Round 21
// 319.410 us; speedup vs baseline: 1.0635x; 1.0009x over previous
//
#include <hip/hip_runtime.h>
#include <stdint.h>

#define DEVI __device__ __forceinline__

typedef __attribute__((ext_vector_type(8))) uint16_t u16x8;
typedef __attribute__((ext_vector_type(4))) uint16_t u16x4v;
typedef __attribute__((ext_vector_type(4))) uint32_t u32x4;
typedef __attribute__((ext_vector_type(8))) __bf16 bf16x8;
typedef __attribute__((ext_vector_type(4))) float f32x4;
typedef __attribute__((ext_vector_type(16))) float f32x16;

DEVI uint16_t f2bf(float x) {
  union { float f; uint32_t u; } v; v.f = x;
  return (uint16_t)((v.u + 0x7fffu + ((v.u >> 16) & 1u)) >> 16);
}

DEVI uint16_t f2bfn(float f) {
  __bf16 h = (__bf16)f;
  return __builtin_bit_cast(uint16_t, h);
}

DEVI f32x4 mfma16(u16x8 a, u16x8 b, f32x4 c) {
  return __builtin_amdgcn_mfma_f32_16x16x32_bf16(
      __builtin_bit_cast(bf16x8, a), __builtin_bit_cast(bf16x8, b), c, 0, 0, 0);
}

DEVI f32x16 mfma32(u16x8 a, u16x8 b, f32x16 c) {
  return __builtin_amdgcn_mfma_f32_32x32x16_bf16(
      __builtin_bit_cast(bf16x8, a), __builtin_bit_cast(bf16x8, b), c, 0, 0, 0);
}

DEVI void async16(void* lds, const void* g) {
  __builtin_amdgcn_global_load_lds(
      (const __attribute__((address_space(1))) uint32_t*)g,
      (__attribute__((address_space(3))) uint32_t*)lds, 16, 0, 0);
}

// 1/sqrt(128) * log2(e): softmax computed in exp2 domain, scale folded into Q.
#define QSC 0.12751742925f

// ---------------- elementwise f32 -> bf16 ----------------
__global__ void cvt_f32_bf16(const float* __restrict__ in, uint16_t* __restrict__ out, int n4) {
  int i = blockIdx.x * blockDim.x + threadIdx.x;
  const int st = gridDim.x * blockDim.x;
  for (; i < n4; i += st) {
    float4 v = ((const float4*)in)[i];
    u16x4v o;
    o[0] = f2bf(v.x); o[1] = f2bf(v.y); o[2] = f2bf(v.z); o[3] = f2bf(v.w);
    ((u16x4v*)out)[i] = o;
  }
}

// ------------- transpose + convert: f32 [K][N] -> bf16 [N][K] -------------
__global__ void transp_cvt(const float* __restrict__ in, uint16_t* __restrict__ out,
                           int K, int N) {
  __shared__ float Ws[64][65];
  const int n0 = blockIdx.x * 64, k0 = blockIdx.y * 64;
  const int t = threadIdx.x;
  const int r = t >> 4, c = (t & 15) << 2;
#pragma unroll
  for (int it = 0; it < 4; ++it) {
    float4 v = *(const float4*)&in[(size_t)(k0 + it * 16 + r) * N + n0 + c];
    Ws[it * 16 + r][c] = v.x; Ws[it * 16 + r][c + 1] = v.y;
    Ws[it * 16 + r][c + 2] = v.z; Ws[it * 16 + r][c + 3] = v.w;
  }
  __syncthreads();
#pragma unroll
  for (int it = 0; it < 4; ++it) {
    const int rr = it * 16 + r;   // n index in tile
    const int cc = c;             // k index in tile
    ushort4 o;
    o.x = f2bf(Ws[cc][rr]);     o.y = f2bf(Ws[cc + 1][rr]);
    o.z = f2bf(Ws[cc + 2][rr]); o.w = f2bf(Ws[cc + 3][rr]);
    *(ushort4*)&out[(size_t)(n0 + rr) * K + k0 + cc] = o;
  }
}

// ------ qkv GEMM: 256x192 tile, SINGLE-phase x 48-MFMA (round-21) ------
// Model (r18 null, r19/r20 wins): GEMM time ~ phase_count x fixed skeleton.
// Phases halve 64 -> 32/block by merging the K-tile into ONE phase.
// Buffer safety for staging t+2 into the buffer read THIS tile (2 bufs):
//  1. ds_read all 20 frags (A 8 + B 12)
//  2. lgkmcnt(0) + sched_barrier  (own reads done; rule-18 fence)
//  3. s_barrier                   (ALL waves' reads done -> buf is dead)
//  4. glds A(t+2),B(t+2) -> buf[t&1] (7 loads)
//  5. vmcnt(7): newest 7 = t+2's; everything older (incl. t+1) landed
//  6. 48 MFMA (pure-reg; no barrier needed before)
//  7. s_barrier (publishes step-5 guarantee before anyone reads buf^1)
// Induction from prologue (tiles 0,1 staged, vmcnt(0)). Tail: vmcnt(0).
// V^T fused epilogue (r16 verified). T2 chunk swizzle both sides.
__global__ __launch_bounds__(512, 1)
void gemm_qkv(const uint16_t* __restrict__ A, const uint16_t* __restrict__ Bt,
              const float* __restrict__ bias,
              uint16_t* __restrict__ q, uint16_t* __restrict__ kk, uint16_t* __restrict__ vt,
              int M, int N, int K) {
  constexpr int BK = 64;
  __shared__ uint16_t As[2][256 * BK];   // 64 KB
  __shared__ uint16_t Bs[2][192 * BK];   // 48 KB
  int bid = (int)blockIdx.x;
  const int q8 = (int)gridDim.x >> 3;
  bid = (bid & 7) * q8 + (bid >> 3);
  const int nbn = N / 192;
  const int brow = (bid / nbn) << 8;
  const int bcol = (bid % nbn) * 192;
  const int t = threadIdx.x;
  const int wid = t >> 6, lane = t & 63;
  const int wm = wid >> 1, wn = wid & 1;          // 4 x 2 wave grid (64 x 96 per wave)
  const int lr = lane & 15, g = lane >> 4, l7 = lr & 7;

  const int logch = (((t & 7) ^ ((t >> 3) & 7)) << 3);
  const uint16_t* Asrc = A + (size_t)(brow + (t >> 3)) * K + logch;
  const uint16_t* Bsrc = Bt + (size_t)(bcol + (t >> 3)) * K + logch;
  const size_t skip64 = (size_t)64 * K;
  const int dt = t * 8;

  auto stageA = [&](int buf, int k0) {
#pragma unroll
    for (int l = 0; l < 4; ++l)
      async16(&As[buf][l * 4096 + dt], Asrc + (size_t)l * skip64 + k0);
  };
  auto stageB = [&](int buf, int k0) {
#pragma unroll
    for (int l = 0; l < 3; ++l)
      async16(&Bs[buf][l * 4096 + dt], Bsrc + (size_t)l * skip64 + k0);
  };

  f32x4 acc[4][6];
#pragma unroll
  for (int i = 0; i < 4; ++i)
#pragma unroll
    for (int j = 0; j < 6; ++j) acc[i][j] = f32x4{0.f, 0.f, 0.f, 0.f};

  const int nt = K / BK;
  stageA(0, 0); stageB(0, 0);
  if (nt > 1) { stageA(1, BK); stageB(1, BK); }
  asm volatile("s_waitcnt vmcnt(0)" ::: "memory");
  __builtin_amdgcn_s_barrier();

  for (int tt = 0; tt < nt; ++tt) {
    const int buf = tt & 1;
    u16x8 bfr[6][2], af[4][2];
#pragma unroll
    for (int j = 0; j < 6; ++j) {
      const int brw = wn * 96 + j * 16 + lr;
#pragma unroll
      for (int s = 0; s < 2; ++s)
        bfr[j][s] = *(const u16x8*)&Bs[buf][brw * 64 + ((((s << 2) + g) ^ l7) << 3)];
    }
#pragma unroll
    for (int ii = 0; ii < 4; ++ii) {
      const int arow = wm * 64 + ii * 16 + lr;
#pragma unroll
      for (int s = 0; s < 2; ++s)
        af[ii][s] = *(const u16x8*)&As[buf][arow * 64 + ((((s << 2) + g) ^ l7) << 3)];
    }
    asm volatile("s_waitcnt lgkmcnt(0)" ::: "memory");
    __builtin_amdgcn_sched_barrier(0);
    __builtin_amdgcn_s_barrier();          // all waves' reads of buf complete
    if (tt + 2 < nt) {
      stageA(buf, (tt + 2) * BK);          // buf is dead; reuse for t+2
      stageB(buf, (tt + 2) * BK);
      asm volatile("s_waitcnt vmcnt(7)" ::: "memory");  // t+1 proven landed
    } else {
      asm volatile("s_waitcnt vmcnt(0)" ::: "memory");
    }
    __builtin_amdgcn_s_setprio(1);
#pragma unroll
    for (int ii = 0; ii < 4; ++ii)
#pragma unroll
      for (int j = 0; j < 6; ++j)
#pragma unroll
        for (int s = 0; s < 2; ++s)
          acc[ii][j] = mfma16(af[ii][s], bfr[j][s], acc[ii][j]);
    __builtin_amdgcn_s_setprio(0);
    __builtin_amdgcn_s_barrier();          // publish vmcnt guarantee
  }

#pragma unroll
  for (int i = 0; i < 4; ++i) {
#pragma unroll
    for (int j = 0; j < 6; ++j) {
      const int col = bcol + wn * 96 + j * 16 + lr;
      const float bb = bias[col];
      const int rowb = brow + wm * 64 + i * 16 + (g << 2);
      const int b_ = rowb >> 11, ttb = rowb & 2047;   // r-span stays in one seq
      const int d = col & 127;
      float vals[4];
#pragma unroll
      for (int r = 0; r < 4; ++r) vals[r] = acc[i][j][r] + bb;
      if (col < 2048) {
        const int hh = col >> 7;
#pragma unroll
        for (int r = 0; r < 4; ++r)
          q[((size_t)((b_ * 16 + hh) * 2048 + ttb + r) << 7) + d] = f2bf(vals[r] * QSC);
      } else if (col < 2560) {
        const int hh = (col - 2048) >> 7;
#pragma unroll
        for (int r = 0; r < 4; ++r)
          kk[((size_t)((b_ * 4 + hh) * 2048 + ttb + r) << 7) + d] = f2bf(vals[r]);
      } else {
        const int hh = (col - 2560) >> 7;
        u16x4v pk;
#pragma unroll
        for (int r = 0; r < 4; ++r) pk[r] = f2bf(vals[r]);
        *(u16x4v*)&vt[(((size_t)((b_ * 4 + hh) * 128 + d)) << 11) + ttb] = pk;
      }
    }
  }
}

// ------ proj GEMM: 256x256, 2-phase x 32-MFMA (round-20, verified) ------
__global__ __launch_bounds__(512, 1)
void gemm_proj(const uint16_t* __restrict__ A, const uint16_t* __restrict__ Bt,
               const float* __restrict__ bias, float* __restrict__ outF,
               int M, int N, int K) {
  constexpr int BK = 64;
  __shared__ uint16_t As[2][256 * BK];   // 64 KB
  __shared__ uint16_t Bs[2][256 * BK];   // 64 KB
  int bid = (int)blockIdx.x;
  const int q8 = (int)gridDim.x >> 3;
  bid = (bid & 7) * q8 + (bid >> 3);
  const int nbn = N >> 8;
  const int brow = (bid / nbn) << 8;
  const int bcol = (bid % nbn) << 8;
  const int t = threadIdx.x;
  const int wid = t >> 6, lane = t & 63;
  const int wm = wid >> 2, wn = wid & 3;          // 2 x 4 wave grid
  const int lr = lane & 15, g = lane >> 4;
  const int l7 = lr & 7;

  const int sr0 = t >> 3;
  const int logch = (((t & 7) ^ ((t >> 3) & 7)) << 3);
  const uint16_t* Asrc0 = A + (size_t)(brow + sr0) * K + logch;
  const uint16_t* Asrc1 = A + (size_t)(brow + 64 + sr0) * K + logch;
  const uint16_t* Bsrc0 = Bt + (size_t)(bcol + sr0) * K + logch;
  const uint16_t* Bsrc1 = Bt + (size_t)(bcol + 64 + sr0) * K + logch;
  const size_t hskip = (size_t)128 * K;
  const int d0 = t * 8, d1 = 4096 + t * 8;

  auto stageA = [&](int buf, int k0) {
    async16(&As[buf][d0], Asrc0 + k0);
    async16(&As[buf][d1], Asrc1 + k0);
    async16(&As[buf][8192 + d0], Asrc0 + hskip + k0);
    async16(&As[buf][8192 + d1], Asrc1 + hskip + k0);
  };
  auto stageB = [&](int buf, int k0) {
    async16(&Bs[buf][d0], Bsrc0 + k0);
    async16(&Bs[buf][d1], Bsrc1 + k0);
    async16(&Bs[buf][8192 + d0], Bsrc0 + hskip + k0);
    async16(&Bs[buf][8192 + d1], Bsrc1 + hskip + k0);
  };

  f32x4 acc[8][4];
#pragma unroll
  for (int i = 0; i < 8; ++i)
#pragma unroll
    for (int j = 0; j < 4; ++j) acc[i][j] = f32x4{0.f, 0.f, 0.f, 0.f};

  const int nt = K / BK;
  stageA(0, 0); stageB(0, 0);
  if (nt > 1) stageB(1, BK);
  asm volatile("s_waitcnt vmcnt(0)" ::: "memory");
  __builtin_amdgcn_s_barrier();

  for (int tt = 0; tt < nt; ++tt) {
    const int buf = tt & 1;
    u16x8 bfr[4][2];
#pragma unroll
    for (int p = 0; p < 2; ++p) {
      if (p == 0) {
#pragma unroll
        for (int j = 0; j < 4; ++j) {
          const int brw = wn * 64 + j * 16 + lr;
#pragma unroll
          for (int s = 0; s < 2; ++s)
            bfr[j][s] = *(const u16x8*)&Bs[buf][brw * 64 + ((((s << 2) + g) ^ l7) << 3)];
        }
      }
      u16x8 af[4][2];
#pragma unroll
      for (int ii = 0; ii < 4; ++ii) {
        const int arow = wm * 128 + (p * 4 + ii) * 16 + lr;
#pragma unroll
        for (int s = 0; s < 2; ++s)
          af[ii][s] = *(const u16x8*)&As[buf][arow * 64 + ((((s << 2) + g) ^ l7) << 3)];
      }
      if (p == 0) {
        if (tt + 1 < nt) stageA(buf ^ 1, (tt + 1) * BK);
      } else {
        if (tt + 2 < nt) {
          stageB(buf, (tt + 2) * BK);
          asm volatile("s_waitcnt vmcnt(4)" ::: "memory");
        } else {
          asm volatile("s_waitcnt vmcnt(0)" ::: "memory");
        }
      }
      __builtin_amdgcn_s_barrier();
      __builtin_amdgcn_s_setprio(1);
#pragma unroll
      for (int ii = 0; ii < 4; ++ii)
#pragma unroll
        for (int j = 0; j < 4; ++j)
#pragma unroll
          for (int s = 0; s < 2; ++s)
            acc[p * 4 + ii][j] = mfma16(af[ii][s], bfr[j][s], acc[p * 4 + ii][j]);
      __builtin_amdgcn_s_setprio(0);
      __builtin_amdgcn_s_barrier();
    }
  }

#pragma unroll
  for (int i = 0; i < 8; ++i) {
#pragma unroll
    for (int j = 0; j < 4; ++j) {
      const int col = bcol + wn * 64 + j * 16 + lr;
      const float bb = bias[col];
#pragma unroll
      for (int r = 0; r < 4; ++r) {
        const int row = brow + wm * 128 + i * 16 + (g << 2) + r;
        outF[(size_t)row * N + col] = acc[i][j][r] + bb;
      }
    }
  }
}

// ------------- flash attention (causal, GQA 4:1) -------------
// ROUND-15 attn verbatim (best verified: 137 us, 92 VGPR, no spill).
__global__ __launch_bounds__(512, 1)
void attn_fwd(const uint16_t* __restrict__ Q,   // [B*16][T][128], pre-scaled by QSC
              const uint16_t* __restrict__ Kg,  // [B*4][T][128]
              const uint16_t* __restrict__ Vt,  // [B*4][128][T]
              uint16_t* __restrict__ Y,         // [B*T][2048], col offset h*128
              int T) {
  __shared__ __align__(16) uint16_t Ks[2][64 * 128];   // 32 KB (dbuf)
  __shared__ __align__(16) uint16_t Vs[128 * 64];      // 16 KB (single)
  const int id = (int)blockIdx.x;
  const int x = id & 7;
  const int h = (id >> 3) & 15, b = (id >> 7) & 3;
  const int qb = (id & 256) ? 7 - x : x;      // complementary across bit 8
  const int hkv = h >> 2;

  const int t = threadIdx.x, w = t >> 6, lane = t & 63;
  const int ql = lane & 31, b5 = lane >> 5;
  const int swzK = (ql & 15) << 3;
  const int swzV = (ql & 7) << 3;

  const uint16_t* Qp = Q + ((size_t)(b * 16 + h) * T + qb * 256) * 128;
  const uint16_t* Kp = Kg + (size_t)(b * 4 + hkv) * T * 128;
  const uint16_t* Vp = Vt + (size_t)(b * 4 + hkv) * 128 * T;

  auto stageK = [&](int buf, int kv0) {
#pragma unroll
    for (int l = 0; l < 2; ++l) {
      const int s = l * 512 + t;
      const int row = s >> 4;                       // 0..63
      const int cl = (s & 15) ^ (row & 15);
      async16(&Ks[buf][s * 8], &Kp[(size_t)(kv0 + row) * 128 + cl * 8]);
    }
  };
  auto stageV = [&](int kv0) {
#pragma unroll
    for (int l = 0; l < 2; ++l) {
      const int s = l * 512 + t;
      const int row = s >> 3;                       // 0..127
      const int cl = (s & 7) ^ (row & 7);
      async16(&Vs[s * 8], &Vp[(size_t)row * T + kv0 + cl * 8]);
    }
  };

  const int row0 = qb * 256 + w * 32;
  const int qrow = row0 + ql;

  u16x8 qf[8];
#pragma unroll
  for (int kc = 0; kc < 8; ++kc)
    qf[kc] = *(const u16x8*)&Qp[(size_t)(w * 32 + ql) * 128 + kc * 16 + b5 * 8];

  f32x16 o[4];  // O^T: lane holds O[d=32db+(reg&3)+8(reg>>2)+4b5][q=ql]
#pragma unroll
  for (int db = 0; db < 4; ++db)
#pragma unroll
    for (int r = 0; r < 16; ++r) o[db][r] = 0.f;
  float mrow = -3e38f, lrow = 0.f;

  const int ntiles = 4 * qb + 4;
  const int myn = 4 * qb + (w >> 1) + 1;  // waves skip fully-masked tail tiles

  stageK(0, 0);
  __syncthreads();

  int cur = 0;
  for (int tile = 0; tile < ntiles; ++tile) {
    const int kv0 = tile << 6;
    stageV(kv0);
    if (tile + 1 < ntiles) stageK(cur ^ 1, (tile + 1) << 6);

    const bool run = tile < myn;
    f32x16 s[2];
    u16x8 pa[4];
    if (run) {
#pragma unroll
      for (int m = 0; m < 2; ++m)
#pragma unroll
        for (int r = 0; r < 16; ++r) s[m][r] = 0.f;
      __builtin_amdgcn_s_setprio(1);
#pragma unroll
      for (int kc = 0; kc < 8; ++kc) {
        const int cc = (kc * 16 + b5 * 8) ^ swzK;
        u16x8 k0f = *(const u16x8*)&Ks[cur][ql * 128 + cc];
        u16x8 k1f = *(const u16x8*)&Ks[cur][(32 + ql) * 128 + cc];
        s[0] = mfma32(k0f, qf[kc], s[0]);
        s[1] = mfma32(k1f, qf[kc], s[1]);
      }
      __builtin_amdgcn_s_setprio(0);

      // causal mask
      if (kv0 + 63 > row0) {
#pragma unroll
        for (int m = 0; m < 2; ++m)
#pragma unroll
          for (int r = 0; r < 16; ++r) {
            const int kg = kv0 + 32 * m + (r & 3) + 8 * (r >> 2) + 4 * b5;
            if (kg > qrow) s[m][r] = -3e38f;
          }
      }
      // online softmax: tree max (dep depth 5)
      float mt[16];
#pragma unroll
      for (int r = 0; r < 16; ++r) mt[r] = fmaxf(s[0][r], s[1][r]);
#pragma unroll
      for (int st = 8; st >= 1; st >>= 1)
#pragma unroll
        for (int r = 0; r < st; ++r) mt[r] = fmaxf(mt[r], mt[r + st]);
      float mx = fmaxf(mt[0], __shfl_xor(mt[0], 32));
      // defer-max (THR=8)
      const bool defer = __all(mx <= mrow + 8.f);
      const float mnew = defer ? mrow : fmaxf(mrow, mx);
      const float sc = defer ? 1.f : exp2f(mrow - mnew);
#pragma unroll
      for (int m = 0; m < 2; ++m)
#pragma unroll
        for (int r = 0; r < 16; ++r) s[m][r] = exp2f(s[m][r] - mnew);
      // tree sum (dep depth 5)
      float pt[16];
#pragma unroll
      for (int r = 0; r < 16; ++r) pt[r] = s[0][r] + s[1][r];
#pragma unroll
      for (int st = 8; st >= 1; st >>= 1)
#pragma unroll
        for (int r = 0; r < st; ++r) pt[r] += pt[r + st];
      float ps = pt[0] + __shfl_xor(pt[0], 32);
      mrow = mnew;
      lrow = lrow * sc + ps;
      if (!defer) {
#pragma unroll
        for (int db = 0; db < 4; ++db)
#pragma unroll
          for (int r = 0; r < 16; ++r) o[db][r] *= sc;
      }

      // P -> B-operand fragments, fully in-register (cross-b5 exchange only)
#pragma unroll
      for (int m = 0; m < 2; ++m) {
        uint32_t pw[4][2];
#pragma unroll
        for (int a = 0; a < 4; ++a)
#pragma unroll
          for (int hh = 0; hh < 2; ++hh)
            pw[a][hh] = (uint32_t)f2bfn(s[m][4 * a + 2 * hh]) |
                        ((uint32_t)f2bfn(s[m][4 * a + 2 * hh + 1]) << 16);
#pragma unroll
        for (int c = 0; c < 2; ++c) {
          uint32_t wd[4];
#pragma unroll
          for (int hh = 0; hh < 2; ++hh) {
            const uint32_t mine  = b5 ? pw[2 * c + 1][hh] : pw[2 * c][hh];
            const uint32_t yours = b5 ? pw[2 * c][hh] : pw[2 * c + 1][hh];
            const uint32_t xw = (uint32_t)__shfl_xor((int)yours, 32);
            wd[hh] = b5 ? xw : mine;
            wd[2 + hh] = b5 ? mine : xw;
          }
          u32x4 tmp = {wd[0], wd[1], wd[2], wd[3]};
          pa[2 * m + c] = __builtin_bit_cast(u16x8, tmp);
        }
      }
    }
    __syncthreads();   // drains V(t) (+K(t+1)); all QK reads of Ks[cur] done

    if (run) {
      __builtin_amdgcn_s_setprio(1);
#pragma unroll
      for (int db = 0; db < 4; ++db) {
#pragma unroll
        for (int kf = 0; kf < 4; ++kf) {
          u16x8 vf = *(const u16x8*)&Vs[(32 * db + ql) * 64 +
                                        ((kf * 16 + b5 * 8) ^ swzV)];
          o[db] = mfma32(vf, pa[kf], o[db]);
        }
      }
      __builtin_amdgcn_s_setprio(0);
    }
    __syncthreads();   // Vs consumed -> next tile may overwrite
    cur ^= 1;
  }

  uint16_t* Yp = Y + ((size_t)(b * T + row0 + ql)) * 2048 + h * 128 + b5 * 4;
  const float inv = 1.f / lrow;
#pragma unroll
  for (int db = 0; db < 4; ++db)
#pragma unroll
    for (int a = 0; a < 4; ++a) {
      u16x4v pk;
#pragma unroll
      for (int r = 0; r < 4; ++r) pk[r] = f2bfn(o[db][4 * a + r] * inv);
      *(u16x4v*)&Yp[db * 32 + a * 8] = pk;
    }
}

extern "C" void kernel_launch(void* const* d_in, const int* in_sizes, int n_in,
                              void* d_out, int out_size, void* d_ws, size_t ws_size,
                              hipStream_t stream) {
  const float* x      = (const float*)d_in[0];
  const float* W_attn = (const float*)d_in[1];
  const float* b_attn = (const float*)d_in[2];
  const float* W_proj = (const float*)d_in[3];
  const float* b_proj = (const float*)d_in[4];
  float* out = (float*)d_out;

  const int B = 4, T = 2048, C = 2048, H = 16, HKV = 4, HS = 128;
  const int M = B * T;               // 8192
  const int Nqkv = C + 2 * HKV * HS; // 3072

  uint8_t* ws = (uint8_t*)d_ws;
  size_t off = 0;
  auto alloc = [&](size_t bytes) {
    void* p = ws + off;
    off += (bytes + 255) & ~(size_t)255;
    return p;
  };
  uint16_t* xb  = (uint16_t*)alloc((size_t)M * C * 2);      // reused as yb after qkv
  uint16_t* WaT = (uint16_t*)alloc((size_t)Nqkv * C * 2);
  uint16_t* WpT = (uint16_t*)alloc((size_t)C * C * 2);
  uint16_t* qb  = (uint16_t*)alloc((size_t)B * H * T * HS * 2);
  uint16_t* kb  = (uint16_t*)alloc((size_t)B * HKV * T * HS * 2);
  uint16_t* vtb = (uint16_t*)alloc((size_t)B * HKV * HS * T * 2);  // V^T direct
  uint16_t* yb  = xb;

  cvt_f32_bf16<<<2048, 256, 0, stream>>>(x, xb, M * C / 4);
  transp_cvt<<<dim3(Nqkv / 64, C / 64), 256, 0, stream>>>(W_attn, WaT, C, Nqkv);
  transp_cvt<<<dim3(C / 64, C / 64), 256, 0, stream>>>(W_proj, WpT, C, C);
  gemm_qkv<<<dim3((M / 256) * (Nqkv / 192)), 512, 0, stream>>>(
      xb, WaT, b_attn, qb, kb, vtb, M, Nqkv, C);
  attn_fwd<<<dim3(512), 512, 0, stream>>>(qb, kb, vtb, yb, T);
  gemm_proj<<<dim3((M / 256) * (C / 256)), 512, 0, stream>>>(
      yb, WpT, b_proj, out, M, C, C);
}

// Round 22
// 307.871 us; speedup vs baseline: 1.1033x; 1.0375x over previous
//
#include <hip/hip_runtime.h>
#include <stdint.h>

#define DEVI __device__ __forceinline__

typedef __attribute__((ext_vector_type(8))) uint16_t u16x8;
typedef __attribute__((ext_vector_type(4))) uint16_t u16x4v;
typedef __attribute__((ext_vector_type(4))) uint32_t u32x4;
typedef __attribute__((ext_vector_type(8))) __bf16 bf16x8;
typedef __attribute__((ext_vector_type(4))) float f32x4;
typedef __attribute__((ext_vector_type(16))) float f32x16;

DEVI uint16_t f2bf(float x) {
  union { float f; uint32_t u; } v; v.f = x;
  return (uint16_t)((v.u + 0x7fffu + ((v.u >> 16) & 1u)) >> 16);
}

DEVI uint16_t f2bfn(float f) {
  __bf16 h = (__bf16)f;
  return __builtin_bit_cast(uint16_t, h);
}

DEVI f32x4 mfma16(u16x8 a, u16x8 b, f32x4 c) {
  return __builtin_amdgcn_mfma_f32_16x16x32_bf16(
      __builtin_bit_cast(bf16x8, a), __builtin_bit_cast(bf16x8, b), c, 0, 0, 0);
}

DEVI f32x16 mfma32(u16x8 a, u16x8 b, f32x16 c) {
  return __builtin_amdgcn_mfma_f32_32x32x16_bf16(
      __builtin_bit_cast(bf16x8, a), __builtin_bit_cast(bf16x8, b), c, 0, 0, 0);
}

DEVI void async16(void* lds, const void* g) {
  __builtin_amdgcn_global_load_lds(
      (const __attribute__((address_space(1))) uint32_t*)g,
      (__attribute__((address_space(3))) uint32_t*)lds, 16, 0, 0);
}

// 1/sqrt(128) * log2(e): softmax computed in exp2 domain, scale folded into Q.
#define QSC 0.12751742925f

// ---------------- elementwise f32 -> bf16 ----------------
__global__ void cvt_f32_bf16(const float* __restrict__ in, uint16_t* __restrict__ out, int n4) {
  int i = blockIdx.x * blockDim.x + threadIdx.x;
  const int st = gridDim.x * blockDim.x;
  for (; i < n4; i += st) {
    float4 v = ((const float4*)in)[i];
    u16x4v o;
    o[0] = f2bf(v.x); o[1] = f2bf(v.y); o[2] = f2bf(v.z); o[3] = f2bf(v.w);
    ((u16x4v*)out)[i] = o;
  }
}

// ------------- transpose + convert: f32 [K][N] -> bf16 [N][K] -------------
__global__ void transp_cvt(const float* __restrict__ in, uint16_t* __restrict__ out,
                           int K, int N) {
  __shared__ float Ws[64][65];
  const int n0 = blockIdx.x * 64, k0 = blockIdx.y * 64;
  const int t = threadIdx.x;
  const int r = t >> 4, c = (t & 15) << 2;
#pragma unroll
  for (int it = 0; it < 4; ++it) {
    float4 v = *(const float4*)&in[(size_t)(k0 + it * 16 + r) * N + n0 + c];
    Ws[it * 16 + r][c] = v.x; Ws[it * 16 + r][c + 1] = v.y;
    Ws[it * 16 + r][c + 2] = v.z; Ws[it * 16 + r][c + 3] = v.w;
  }
  __syncthreads();
#pragma unroll
  for (int it = 0; it < 4; ++it) {
    const int rr = it * 16 + r;   // n index in tile
    const int cc = c;             // k index in tile
    ushort4 o;
    o.x = f2bf(Ws[cc][rr]);     o.y = f2bf(Ws[cc + 1][rr]);
    o.z = f2bf(Ws[cc + 2][rr]); o.w = f2bf(Ws[cc + 3][rr]);
    *(ushort4*)&out[(size_t)(n0 + rr) * K + k0 + cc] = o;
  }
}

// ------ qkv GEMM: 256x192 tile, SINGLE-phase x 48-MFMA (round-21, kept) ------
__global__ __launch_bounds__(512, 1)
void gemm_qkv(const uint16_t* __restrict__ A, const uint16_t* __restrict__ Bt,
              const float* __restrict__ bias,
              uint16_t* __restrict__ q, uint16_t* __restrict__ kk, uint16_t* __restrict__ vt,
              int M, int N, int K) {
  constexpr int BK = 64;
  __shared__ uint16_t As[2][256 * BK];   // 64 KB
  __shared__ uint16_t Bs[2][192 * BK];   // 48 KB
  int bid = (int)blockIdx.x;
  const int q8 = (int)gridDim.x >> 3;
  bid = (bid & 7) * q8 + (bid >> 3);
  const int nbn = N / 192;
  const int brow = (bid / nbn) << 8;
  const int bcol = (bid % nbn) * 192;
  const int t = threadIdx.x;
  const int wid = t >> 6, lane = t & 63;
  const int wm = wid >> 1, wn = wid & 1;          // 4 x 2 wave grid (64 x 96 per wave)
  const int lr = lane & 15, g = lane >> 4, l7 = lr & 7;

  const int logch = (((t & 7) ^ ((t >> 3) & 7)) << 3);
  const uint16_t* Asrc = A + (size_t)(brow + (t >> 3)) * K + logch;
  const uint16_t* Bsrc = Bt + (size_t)(bcol + (t >> 3)) * K + logch;
  const size_t skip64 = (size_t)64 * K;
  const int dt = t * 8;

  auto stageA = [&](int buf, int k0) {
#pragma unroll
    for (int l = 0; l < 4; ++l)
      async16(&As[buf][l * 4096 + dt], Asrc + (size_t)l * skip64 + k0);
  };
  auto stageB = [&](int buf, int k0) {
#pragma unroll
    for (int l = 0; l < 3; ++l)
      async16(&Bs[buf][l * 4096 + dt], Bsrc + (size_t)l * skip64 + k0);
  };

  f32x4 acc[4][6];
#pragma unroll
  for (int i = 0; i < 4; ++i)
#pragma unroll
    for (int j = 0; j < 6; ++j) acc[i][j] = f32x4{0.f, 0.f, 0.f, 0.f};

  const int nt = K / BK;
  stageA(0, 0); stageB(0, 0);
  if (nt > 1) { stageA(1, BK); stageB(1, BK); }
  asm volatile("s_waitcnt vmcnt(0)" ::: "memory");
  __builtin_amdgcn_s_barrier();

  for (int tt = 0; tt < nt; ++tt) {
    const int buf = tt & 1;
    u16x8 bfr[6][2], af[4][2];
#pragma unroll
    for (int j = 0; j < 6; ++j) {
      const int brw = wn * 96 + j * 16 + lr;
#pragma unroll
      for (int s = 0; s < 2; ++s)
        bfr[j][s] = *(const u16x8*)&Bs[buf][brw * 64 + ((((s << 2) + g) ^ l7) << 3)];
    }
#pragma unroll
    for (int ii = 0; ii < 4; ++ii) {
      const int arow = wm * 64 + ii * 16 + lr;
#pragma unroll
      for (int s = 0; s < 2; ++s)
        af[ii][s] = *(const u16x8*)&As[buf][arow * 64 + ((((s << 2) + g) ^ l7) << 3)];
    }
    asm volatile("s_waitcnt lgkmcnt(0)" ::: "memory");
    __builtin_amdgcn_sched_barrier(0);
    __builtin_amdgcn_s_barrier();          // all waves' reads of buf complete
    if (tt + 2 < nt) {
      stageA(buf, (tt + 2) * BK);          // buf is dead; reuse for t+2
      stageB(buf, (tt + 2) * BK);
      asm volatile("s_waitcnt vmcnt(7)" ::: "memory");  // t+1 proven landed
    } else {
      asm volatile("s_waitcnt vmcnt(0)" ::: "memory");
    }
    __builtin_amdgcn_s_setprio(1);
#pragma unroll
    for (int ii = 0; ii < 4; ++ii)
#pragma unroll
      for (int j = 0; j < 6; ++j)
#pragma unroll
        for (int s = 0; s < 2; ++s)
          acc[ii][j] = mfma16(af[ii][s], bfr[j][s], acc[ii][j]);
    __builtin_amdgcn_s_setprio(0);
    __builtin_amdgcn_s_barrier();          // publish vmcnt guarantee
  }

#pragma unroll
  for (int i = 0; i < 4; ++i) {
#pragma unroll
    for (int j = 0; j < 6; ++j) {
      const int col = bcol + wn * 96 + j * 16 + lr;
      const float bb = bias[col];
      const int rowb = brow + wm * 64 + i * 16 + (g << 2);
      const int b_ = rowb >> 11, ttb = rowb & 2047;   // r-span stays in one seq
      const int d = col & 127;
      float vals[4];
#pragma unroll
      for (int r = 0; r < 4; ++r) vals[r] = acc[i][j][r] + bb;
      if (col < 2048) {
        const int hh = col >> 7;
#pragma unroll
        for (int r = 0; r < 4; ++r)
          q[((size_t)((b_ * 16 + hh) * 2048 + ttb + r) << 7) + d] = f2bf(vals[r] * QSC);
      } else if (col < 2560) {
        const int hh = (col - 2048) >> 7;
#pragma unroll
        for (int r = 0; r < 4; ++r)
          kk[((size_t)((b_ * 4 + hh) * 2048 + ttb + r) << 7) + d] = f2bf(vals[r]);
      } else {
        const int hh = (col - 2560) >> 7;
        u16x4v pk;
#pragma unroll
        for (int r = 0; r < 4; ++r) pk[r] = f2bf(vals[r]);
        *(u16x4v*)&vt[(((size_t)((b_ * 4 + hh) * 128 + d)) << 11) + ttb] = pk;
      }
    }
  }
}

// ------ proj GEMM: 256x256, 2-phase x 32-MFMA (round-20, verified) ------
__global__ __launch_bounds__(512, 1)
void gemm_proj(const uint16_t* __restrict__ A, const uint16_t* __restrict__ Bt,
               const float* __restrict__ bias, float* __restrict__ outF,
               int M, int N, int K) {
  constexpr int BK = 64;
  __shared__ uint16_t As[2][256 * BK];   // 64 KB
  __shared__ uint16_t Bs[2][256 * BK];   // 64 KB
  int bid = (int)blockIdx.x;
  const int q8 = (int)gridDim.x >> 3;
  bid = (bid & 7) * q8 + (bid >> 3);
  const int nbn = N >> 8;
  const int brow = (bid / nbn) << 8;
  const int bcol = (bid % nbn) << 8;
  const int t = threadIdx.x;
  const int wid = t >> 6, lane = t & 63;
  const int wm = wid >> 2, wn = wid & 3;          // 2 x 4 wave grid
  const int lr = lane & 15, g = lane >> 4;
  const int l7 = lr & 7;

  const int sr0 = t >> 3;
  const int logch = (((t & 7) ^ ((t >> 3) & 7)) << 3);
  const uint16_t* Asrc0 = A + (size_t)(brow + sr0) * K + logch;
  const uint16_t* Asrc1 = A + (size_t)(brow + 64 + sr0) * K + logch;
  const uint16_t* Bsrc0 = Bt + (size_t)(bcol + sr0) * K + logch;
  const uint16_t* Bsrc1 = Bt + (size_t)(bcol + 64 + sr0) * K + logch;
  const size_t hskip = (size_t)128 * K;
  const int d0 = t * 8, d1 = 4096 + t * 8;

  auto stageA = [&](int buf, int k0) {
    async16(&As[buf][d0], Asrc0 + k0);
    async16(&As[buf][d1], Asrc1 + k0);
    async16(&As[buf][8192 + d0], Asrc0 + hskip + k0);
    async16(&As[buf][8192 + d1], Asrc1 + hskip + k0);
  };
  auto stageB = [&](int buf, int k0) {
    async16(&Bs[buf][d0], Bsrc0 + k0);
    async16(&Bs[buf][d1], Bsrc1 + k0);
    async16(&Bs[buf][8192 + d0], Bsrc0 + hskip + k0);
    async16(&Bs[buf][8192 + d1], Bsrc1 + hskip + k0);
  };

  f32x4 acc[8][4];
#pragma unroll
  for (int i = 0; i < 8; ++i)
#pragma unroll
    for (int j = 0; j < 4; ++j) acc[i][j] = f32x4{0.f, 0.f, 0.f, 0.f};

  const int nt = K / BK;
  stageA(0, 0); stageB(0, 0);
  if (nt > 1) stageB(1, BK);
  asm volatile("s_waitcnt vmcnt(0)" ::: "memory");
  __builtin_amdgcn_s_barrier();

  for (int tt = 0; tt < nt; ++tt) {
    const int buf = tt & 1;
    u16x8 bfr[4][2];
#pragma unroll
    for (int p = 0; p < 2; ++p) {
      if (p == 0) {
#pragma unroll
        for (int j = 0; j < 4; ++j) {
          const int brw = wn * 64 + j * 16 + lr;
#pragma unroll
          for (int s = 0; s < 2; ++s)
            bfr[j][s] = *(const u16x8*)&Bs[buf][brw * 64 + ((((s << 2) + g) ^ l7) << 3)];
        }
      }
      u16x8 af[4][2];
#pragma unroll
      for (int ii = 0; ii < 4; ++ii) {
        const int arow = wm * 128 + (p * 4 + ii) * 16 + lr;
#pragma unroll
        for (int s = 0; s < 2; ++s)
          af[ii][s] = *(const u16x8*)&As[buf][arow * 64 + ((((s << 2) + g) ^ l7) << 3)];
      }
      if (p == 0) {
        if (tt + 1 < nt) stageA(buf ^ 1, (tt + 1) * BK);
      } else {
        if (tt + 2 < nt) {
          stageB(buf, (tt + 2) * BK);
          asm volatile("s_waitcnt vmcnt(4)" ::: "memory");
        } else {
          asm volatile("s_waitcnt vmcnt(0)" ::: "memory");
        }
      }
      __builtin_amdgcn_s_barrier();
      __builtin_amdgcn_s_setprio(1);
#pragma unroll
      for (int ii = 0; ii < 4; ++ii)
#pragma unroll
        for (int j = 0; j < 4; ++j)
#pragma unroll
          for (int s = 0; s < 2; ++s)
            acc[p * 4 + ii][j] = mfma16(af[ii][s], bfr[j][s], acc[p * 4 + ii][j]);
      __builtin_amdgcn_s_setprio(0);
      __builtin_amdgcn_s_barrier();
    }
  }

#pragma unroll
  for (int i = 0; i < 8; ++i) {
#pragma unroll
    for (int j = 0; j < 4; ++j) {
      const int col = bcol + wn * 64 + j * 16 + lr;
      const float bb = bias[col];
#pragma unroll
      for (int r = 0; r < 4; ++r) {
        const int row = brow + wm * 128 + i * 16 + (g << 2) + r;
        outF[(size_t)row * N + col] = acc[i][j][r] + bb;
      }
    }
  }
}

// ------------- flash attention (causal, GQA 4:1), T15 double-pipeline -------
// ROUND 22: two S-states in flight. Iter t: {stage V(t)->Vs[t&1], stage
// K(t+1)->Ks[(t+1)&1], QK(t) (MFMA), finish(t-1)=mask+softmax+pack+PV(t-1)
// (VALU indep of QK(t) -> overlaps QK's MFMA shadow), ONE __syncthreads}.
// Barriers 2/tile -> 1/tile; V gets a full-iteration prefetch cover.
// Parity safety: V(t) read at t+1, overwritten at t+2 (barrier-separated);
// Ks[t&1] read at t, rewritten at t+1 staging K(t+2). ntiles even -> tiles
// processed in unrolled pairs with NAMED sA/sB states (rule #20: static
// VGPR indexing). Epilogue finishes S(ntiles-1). LDS 64 KB (1 blk/CU).
__global__ __launch_bounds__(512, 1)
void attn_fwd(const uint16_t* __restrict__ Q,   // [B*16][T][128], pre-scaled by QSC
              const uint16_t* __restrict__ Kg,  // [B*4][T][128]
              const uint16_t* __restrict__ Vt,  // [B*4][128][T]
              uint16_t* __restrict__ Y,         // [B*T][2048], col offset h*128
              int T) {
  __shared__ __align__(16) uint16_t Ks[2][64 * 128];   // 32 KB (parity dbuf)
  __shared__ __align__(16) uint16_t Vs[2][128 * 64];   // 32 KB (parity dbuf)
  const int id = (int)blockIdx.x;
  const int x = id & 7;
  const int h = (id >> 3) & 15, b = (id >> 7) & 3;
  const int qb = (id & 256) ? 7 - x : x;      // complementary across bit 8
  const int hkv = h >> 2;

  const int t = threadIdx.x, w = t >> 6, lane = t & 63;
  const int ql = lane & 31, b5 = lane >> 5;
  const int swzK = (ql & 15) << 3;
  const int swzV = (ql & 7) << 3;

  const uint16_t* Qp = Q + ((size_t)(b * 16 + h) * T + qb * 256) * 128;
  const uint16_t* Kp = Kg + (size_t)(b * 4 + hkv) * T * 128;
  const uint16_t* Vp = Vt + (size_t)(b * 4 + hkv) * 128 * T;

  auto stageK = [&](int buf, int kv0) {
#pragma unroll
    for (int l = 0; l < 2; ++l) {
      const int s = l * 512 + t;
      const int row = s >> 4;                       // 0..63
      const int cl = (s & 15) ^ (row & 15);
      async16(&Ks[buf][s * 8], &Kp[(size_t)(kv0 + row) * 128 + cl * 8]);
    }
  };
  auto stageV = [&](int buf, int kv0) {
#pragma unroll
    for (int l = 0; l < 2; ++l) {
      const int s = l * 512 + t;
      const int row = s >> 3;                       // 0..127
      const int cl = (s & 7) ^ (row & 7);
      async16(&Vs[buf][s * 8], &Vp[(size_t)row * T + kv0 + cl * 8]);
    }
  };

  const int row0 = qb * 256 + w * 32;
  const int qrow = row0 + ql;

  u16x8 qf[8];
#pragma unroll
  for (int kc = 0; kc < 8; ++kc)
    qf[kc] = *(const u16x8*)&Qp[(size_t)(w * 32 + ql) * 128 + kc * 16 + b5 * 8];

  f32x16 o[4];  // O^T: lane holds O[d=32db+(reg&3)+8(reg>>2)+4b5][q=ql]
#pragma unroll
  for (int db = 0; db < 4; ++db)
#pragma unroll
    for (int r = 0; r < 16; ++r) o[db][r] = 0.f;
  float mrow = -3e38f, lrow = 0.f;

  const int ntiles = 4 * qb + 4;                 // even
  const int myn = 4 * qb + (w >> 1) + 1;         // waves skip masked tail tiles

  // QK(tp) into sp[0..1] from Ks[tp&1]
  auto qk = [&](int tp, f32x16* sp) {
    sp[0] = 0.f; sp[1] = 0.f;
    const int kbuf = tp & 1;
    __builtin_amdgcn_s_setprio(1);
#pragma unroll
    for (int kc = 0; kc < 8; ++kc) {
      const int cc = (kc * 16 + b5 * 8) ^ swzK;
      u16x8 k0f = *(const u16x8*)&Ks[kbuf][ql * 128 + cc];
      u16x8 k1f = *(const u16x8*)&Ks[kbuf][(32 + ql) * 128 + cc];
      sp[0] = mfma32(k0f, qf[kc], sp[0]);
      sp[1] = mfma32(k1f, qf[kc], sp[1]);
    }
    __builtin_amdgcn_s_setprio(0);
  };

  // finish(tp): mask + online softmax + pack + PV from Vs[tp&1]
  auto finish = [&](int tp, f32x16* sp) {
    const int kv0 = tp << 6;
    if (kv0 + 63 > row0) {
#pragma unroll
      for (int m = 0; m < 2; ++m)
#pragma unroll
        for (int r = 0; r < 16; ++r) {
          const int kg = kv0 + 32 * m + (r & 3) + 8 * (r >> 2) + 4 * b5;
          if (kg > qrow) sp[m][r] = -3e38f;
        }
    }
    float mt[16];
#pragma unroll
    for (int r = 0; r < 16; ++r) mt[r] = fmaxf(sp[0][r], sp[1][r]);
#pragma unroll
    for (int st = 8; st >= 1; st >>= 1)
#pragma unroll
      for (int r = 0; r < st; ++r) mt[r] = fmaxf(mt[r], mt[r + st]);
    float mx = fmaxf(mt[0], __shfl_xor(mt[0], 32));
    const bool defer = __all(mx <= mrow + 8.f);
    const float mnew = defer ? mrow : fmaxf(mrow, mx);
    const float sc = defer ? 1.f : exp2f(mrow - mnew);
#pragma unroll
    for (int m = 0; m < 2; ++m)
#pragma unroll
      for (int r = 0; r < 16; ++r) sp[m][r] = exp2f(sp[m][r] - mnew);
    float pt[16];
#pragma unroll
    for (int r = 0; r < 16; ++r) pt[r] = sp[0][r] + sp[1][r];
#pragma unroll
    for (int st = 8; st >= 1; st >>= 1)
#pragma unroll
      for (int r = 0; r < st; ++r) pt[r] += pt[r + st];
    float ps = pt[0] + __shfl_xor(pt[0], 32);
    mrow = mnew;
    lrow = lrow * sc + ps;
    if (!defer) {
#pragma unroll
      for (int db = 0; db < 4; ++db)
#pragma unroll
        for (int r = 0; r < 16; ++r) o[db][r] *= sc;
    }
    u16x8 pa[4];
#pragma unroll
    for (int m = 0; m < 2; ++m) {
      uint32_t pw[4][2];
#pragma unroll
      for (int a = 0; a < 4; ++a)
#pragma unroll
        for (int hh = 0; hh < 2; ++hh)
          pw[a][hh] = (uint32_t)f2bfn(sp[m][4 * a + 2 * hh]) |
                      ((uint32_t)f2bfn(sp[m][4 * a + 2 * hh + 1]) << 16);
#pragma unroll
      for (int c = 0; c < 2; ++c) {
        uint32_t wd[4];
#pragma unroll
        for (int hh = 0; hh < 2; ++hh) {
          const uint32_t mine  = b5 ? pw[2 * c + 1][hh] : pw[2 * c][hh];
          const uint32_t yours = b5 ? pw[2 * c][hh] : pw[2 * c + 1][hh];
          const uint32_t xw = (uint32_t)__shfl_xor((int)yours, 32);
          wd[hh] = b5 ? xw : mine;
          wd[2 + hh] = b5 ? mine : xw;
        }
        u32x4 tmp = {wd[0], wd[1], wd[2], wd[3]};
        pa[2 * m + c] = __builtin_bit_cast(u16x8, tmp);
      }
    }
    const int vbuf = tp & 1;
    __builtin_amdgcn_s_setprio(1);
#pragma unroll
    for (int db = 0; db < 4; ++db) {
#pragma unroll
      for (int kf = 0; kf < 4; ++kf) {
        u16x8 vf = *(const u16x8*)&Vs[vbuf][(32 * db + ql) * 64 +
                                           ((kf * 16 + b5 * 8) ^ swzV)];
        o[db] = mfma32(vf, pa[kf], o[db]);
      }
    }
    __builtin_amdgcn_s_setprio(0);
  };

  f32x16 sA[2], sB[2];

  stageK(0, 0);
  __syncthreads();

  for (int tile = 0; tile < ntiles; tile += 2) {
    // ---- even tile: QK -> sA, finish sB (tile-1, odd) ----
    stageV(0, tile << 6);
    if (tile + 1 < ntiles) stageK(1, (tile + 1) << 6);
    if (tile < myn) qk(tile, sA);
    if (tile >= 1 && tile - 1 < myn) finish(tile - 1, sB);
    __syncthreads();   // drains V(t)+K(t+1); separates buffer reuse
    // ---- odd tile: QK -> sB, finish sA (tile) ----
    const int t2 = tile + 1;
    stageV(1, t2 << 6);
    if (t2 + 1 < ntiles) stageK(0, (t2 + 1) << 6);
    if (t2 < myn) qk(t2, sB);
    if (t2 - 1 < myn) finish(t2 - 1, sA);
    __syncthreads();
  }
  if (ntiles - 1 < myn) finish(ntiles - 1, sB);   // last tile is odd -> sB

  uint16_t* Yp = Y + ((size_t)(b * T + row0 + ql)) * 2048 + h * 128 + b5 * 4;
  const float inv = 1.f / lrow;
#pragma unroll
  for (int db = 0; db < 4; ++db)
#pragma unroll
    for (int a = 0; a < 4; ++a) {
      u16x4v pk;
#pragma unroll
      for (int r = 0; r < 4; ++r) pk[r] = f2bfn(o[db][4 * a + r] * inv);
      *(u16x4v*)&Yp[db * 32 + a * 8] = pk;
    }
}

extern "C" void kernel_launch(void* const* d_in, const int* in_sizes, int n_in,
                              void* d_out, int out_size, void* d_ws, size_t ws_size,
                              hipStream_t stream) {
  const float* x      = (const float*)d_in[0];
  const float* W_attn = (const float*)d_in[1];
  const float* b_attn = (const float*)d_in[2];
  const float* W_proj = (const float*)d_in[3];
  const float* b_proj = (const float*)d_in[4];
  float* out = (float*)d_out;

  const int B = 4, T = 2048, C = 2048, H = 16, HKV = 4, HS = 128;
  const int M = B * T;               // 8192
  const int Nqkv = C + 2 * HKV * HS; // 3072

  uint8_t* ws = (uint8_t*)d_ws;
  size_t off = 0;
  auto alloc = [&](size_t bytes) {
    void* p = ws + off;
    off += (bytes + 255) & ~(size_t)255;
    return p;
  };
  uint16_t* xb  = (uint16_t*)alloc((size_t)M * C * 2);      // reused as yb after qkv
  uint16_t* WaT = (uint16_t*)alloc((size_t)Nqkv * C * 2);
  uint16_t* WpT = (uint16_t*)alloc((size_t)C * C * 2);
  uint16_t* qb  = (uint16_t*)alloc((size_t)B * H * T * HS * 2);
  uint16_t* kb  = (uint16_t*)alloc((size_t)B * HKV * T * HS * 2);
  uint16_t* vtb = (uint16_t*)alloc((size_t)B * HKV * HS * T * 2);  // V^T direct
  uint16_t* yb  = xb;

  cvt_f32_bf16<<<2048, 256, 0, stream>>>(x, xb, M * C / 4);
  transp_cvt<<<dim3(Nqkv / 64, C / 64), 256, 0, stream>>>(W_attn, WaT, C, Nqkv);
  transp_cvt<<<dim3(C / 64, C / 64), 256, 0, stream>>>(W_proj, WpT, C, C);
  gemm_qkv<<<dim3((M / 256) * (Nqkv / 192)), 512, 0, stream>>>(
      xb, WaT, b_attn, qb, kb, vtb, M, Nqkv, C);
  attn_fwd<<<dim3(512), 512, 0, stream>>>(qb, kb, vtb, yb, T);
  gemm_proj<<<dim3((M / 256) * (C / 256)), 512, 0, stream>>>(
      yb, WpT, b_proj, out, M, C, C);
}